// Round 15
// baseline (284.317 us; speedup 1.0000x reference)
//
#include <hip/hip_runtime.h>
#include <math.h>

#define HDIM 128
#define NBUCK 512   // dst buckets; R2 = ceil(n/512) must be <= 256
#define BINB 128    // blocks in binning grid
#define CH 8192     // edges staged per chunk in k_bin
#define CAP 4096    // bin/cw capacity per bucket (mean 3136, +17 sigma; mult of 4)

typedef unsigned int uint;
typedef unsigned short ushort;
typedef unsigned long long ull;
typedef __attribute__((ext_vector_type(8))) short short8;
typedef __attribute__((ext_vector_type(4))) float f32x4;

// bf16 helpers (bit-level; bf16->fp32 exact, fp32->bf16 RNE)
__device__ __forceinline__ float bflo(uint u){ return __uint_as_float(u<<16); }
__device__ __forceinline__ float bfhi(uint u){ return __uint_as_float(u&0xffff0000u); }
__device__ __forceinline__ ushort f2bf(float f){
  uint x = __float_as_uint(f);
  return (ushort)((x + 0x7fffu + ((x>>16)&1u)) >> 16);
}
__device__ __forceinline__ uint pack2bf(float a, float b){
  return (uint)f2bf(a) | ((uint)f2bf(b)<<16);
}

// ---------- zero the 512 bucket cursors ----------
__global__ void k_z512(int* gcur){
  int i = blockIdx.x*256 + threadIdx.x;
  if (i < NBUCK) gcur[i] = 0;
}

// ---------- single-pass chunked binning ----------
__global__ __launch_bounds__(256) void k_bin(const int* __restrict__ src, const int* __restrict__ dst,
                      int* __restrict__ gcur, uint* __restrict__ bins, int e, int R2){
  __shared__ uint   recs[CH];    // 32KB
  __shared__ ushort qarr[CH];    // 16KB
  __shared__ int    hist[NBUCK]; // 2KB
  __shared__ int    base[NBUCK]; // 2KB
  int t = threadIdx.x;
  int nch = (e + CH - 1)/CH;
  for (int c = blockIdx.x; c < nch; c += gridDim.x){
    int c0 = c*CH;
    int m = min(e - c0, CH);
    for (int u=t; u<NBUCK; u+=256) hist[u]=0;
    __syncthreads();
    for (int j=t; j<m; j+=256){
      int s = __builtin_nontemporal_load(&src[c0+j]);
      int d = __builtin_nontemporal_load(&dst[c0+j]);
      int q = d / R2;
      recs[j] = ((uint)s<<8) | (uint)(d - q*R2);
      qarr[j] = (ushort)q;
      atomicAdd(&hist[q],1);
    }
    __syncthreads();
    for (int u=t; u<NBUCK; u+=256){
      int cn = hist[u];
      base[u] = cn ? atomicAdd(&gcur[u], cn) : 0;
      hist[u] = 0;                       // reuse as placement cursor
    }
    __syncthreads();
    for (int j=t; j<m; j+=256){
      int q = qarr[j];
      int lp = base[q] + atomicAdd(&hist[q],1);
      if (lp < CAP) bins[q*CAP + lp] = recs[j];
    }
    __syncthreads();
  }
}

// ---------- per-bucket CSR build (block-local) + W transpose fold-in ----------
__global__ __launch_bounds__(256) void k_csr(const uint* __restrict__ bins, const int* __restrict__ gcur,
                      const float* __restrict__ x,
                      const float* __restrict__ W1, const float* __restrict__ W2,
                      ushort* __restrict__ Wt1, ushort* __restrict__ Wt2,
                      int* __restrict__ cnt, int* __restrict__ off,
                      float* __restrict__ dis, float* __restrict__ xs, int* __restrict__ cw,
                      int n, int R2){
  __shared__ uint recs[CAP];     // 16KB
  __shared__ int lcnt[256];
  __shared__ int lofs[256];
  __shared__ int tmp[256];
  int q = blockIdx.x;
  int t = threadIdx.x;
  if (q < 64){                   // Wt transpose: 64 blocks x 256 = 16384 entries
    int i = q*256 + t;
    int no = i>>7, k = i&127;
    Wt1[i] = f2bf(W1[k*HDIM+no]);
    Wt2[i] = f2bf(W2[k*HDIM+no]);
  }
  int d0 = q*R2;
  int nloc = min(n - d0, R2);
  if (nloc <= 0) return;
  int estart = q*CAP;
  int m = min(gcur[q], CAP);
  lcnt[t] = 0;
  for (int i = t; i < m; i += 256) recs[i] = bins[estart+i];
  __syncthreads();
  for (int i = t; i < m; i += 256) atomicAdd(&lcnt[recs[i] & 255u], 1);
  __syncthreads();
  int v = (t<nloc) ? lcnt[t] : 0;
  int span = (v+3)&~3;           // 16B-aligned per-node segment
  tmp[t] = span; __syncthreads();
  for (int d=1; d<256; d<<=1){
    int a = (t>=d) ? tmp[t-d] : 0;
    __syncthreads(); tmp[t] += a; __syncthreads();
  }
  int excl = tmp[t] - span;
  if (t<nloc){
    int node = d0 + t;
    cnt[node] = v;
    off[node] = estart + excl;
    float dv = rsqrtf((float)(v+1));
    dis[node] = dv;
    xs[node] = dv*x[node];
    lofs[t] = excl;
    lcnt[t] = 0;                 // reuse as cursor
  }
  __syncthreads();
  for (int i = t; i < m; i += 256){
    uint r = recs[i];
    int dl = r & 255u;
    int pos = estart + lofs[dl] + atomicAdd(&lcnt[dl], 1);
    cw[pos] = (int)(r >> 8);
  }
}

// ---------- scalar aggregation -> tb[i] = (s_i, dis_i) ----------
__global__ void k_sagg(const float* __restrict__ xs, const float* __restrict__ dis,
                       const int* __restrict__ off, const int* __restrict__ cnt,
                       const int* __restrict__ cw, float2* __restrict__ tb, int n){
  int i = blockIdx.x*256 + threadIdx.x;
  if (i>=n) return;
  int b = off[i], e = b + cnt[i];
  float acc = xs[i];
  int k = b;
  for (; k+4<=e; k+=4){
    int4 s4 = *(const int4*)(cw + k);
    acc += (xs[s4.x]+xs[s4.y]) + (xs[s4.z]+xs[s4.w]);
  }
  for (; k<e; ++k) acc += xs[cw[k]];
  float dv = dis[i];
  tb[i] = make_float2(dv*acc, dv);
}

// ---------- layer-1 aggregation via rank-1 reconstruction, shfl-free ----------
// 16 wave-uniform tb loads per batch (L1 broadcast, VMEM pipe) replace the
// 2-shfl-per-edge ds_bpermute storm. Tail via uniform j<rem predication;
// overreads stay in-allocation, pad addresses select node 0 with weight 0.
__global__ __launch_bounds__(256) void k_wagg1s(const float2* __restrict__ tb, const int* __restrict__ off,
                       const int* __restrict__ cnt, const int* __restrict__ cw,
                       const float* __restrict__ W0, const float* __restrict__ b0,
                       uint* __restrict__ g, int n){
  int wave = threadIdx.x>>6, lane = threadIdx.x&63;
  int i = blockIdx.x*4 + wave;
  if (i>=n) return;
  float2 w0 = ((const float2*)W0)[lane];
  float2 b0v = ((const float2*)b0)[lane];
  int b = off[i], e = b + cnt[i];
  float2 ti = tb[i];
  float2 acc;
  acc.x = ti.y * fmaxf(fmaf(ti.x, w0.x, b0v.x), 0.f);
  acc.y = ti.y * fmaxf(fmaf(ti.x, w0.y, b0v.y), 0.f);
  for (int k = b; k < e; k += 16){
    int rem = e - k;                          // wave-uniform, >=1
    const int4* c4 = (const int4*)(cw + k);   // 16B-aligned; overread safe
    int4 v0=c4[0], v1=c4[1], v2=c4[2], v3=c4[3];
    int c[16] = {v0.x,v0.y,v0.z,v0.w, v1.x,v1.y,v1.z,v1.w,
                 v2.x,v2.y,v2.z,v2.w, v3.x,v3.y,v3.z,v3.w};
    float2 t[16];
    #pragma unroll
    for (int j=0;j<16;j++){
      int idx = (j < rem) ? c[j] : 0;         // uniform select -> safe address
      t[j] = tb[idx];                          // independent uniform loads
    }
    #pragma unroll
    for (int j=0;j<16;j++){
      float dj = (j < rem) ? t[j].y : 0.f;
      acc.x = fmaf(dj, fmaxf(fmaf(t[j].x, w0.x, b0v.x), 0.f), acc.x);
      acc.y = fmaf(dj, fmaxf(fmaf(t[j].x, w0.y, b0v.y), 0.f), acc.y);
    }
  }
  __builtin_nontemporal_store(pack2bf(ti.y*acc.x, ti.y*acc.y), &g[(size_t)i*64 + lane]);
}

// ---------- wide aggregation: g_i = dis_i*(hs_i + sum hs[src]); int4 cw loads ----------
__global__ __launch_bounds__(256) void k_wagg(const uint* __restrict__ h, const int* __restrict__ off,
                       const int* __restrict__ cnt, const int* __restrict__ cw,
                       const float* __restrict__ dis, uint* __restrict__ g, int n){
  int wave = threadIdx.x>>6, lane = threadIdx.x&63;
  int i = blockIdx.x*4 + wave;
  if (i>=n) return;
  int b = off[i], e = b + cnt[i];
  uint su = h[(size_t)i*64 + lane];
  float2 acc; acc.x = bflo(su); acc.y = bfhi(su);
  int k = b;
  for (; k+16<=e; k+=16){
    const int4* c4 = (const int4*)(cw + k);   // b is 16B-aligned
    int4 v0 = c4[0], v1 = c4[1], v2 = c4[2], v3 = c4[3];
    int v[16] = {v0.x,v0.y,v0.z,v0.w, v1.x,v1.y,v1.z,v1.w,
                 v2.x,v2.y,v2.z,v2.w, v3.x,v3.y,v3.z,v3.w};
    uint u[16];
    #pragma unroll
    for (int j=0;j<16;j++) u[j] = h[(size_t)v[j]*64 + lane];
    #pragma unroll
    for (int j=0;j<16;j++){ acc.x += bflo(u[j]); acc.y += bfhi(u[j]); }
  }
  for (; k+4<=e; k+=4){
    int4 v4 = *(const int4*)(cw + k);
    uint u0 = h[(size_t)v4.x*64 + lane];
    uint u1 = h[(size_t)v4.y*64 + lane];
    uint u2 = h[(size_t)v4.z*64 + lane];
    uint u3 = h[(size_t)v4.w*64 + lane];
    acc.x += bflo(u0)+bflo(u1)+bflo(u2)+bflo(u3);
    acc.y += bfhi(u0)+bfhi(u1)+bfhi(u2)+bfhi(u3);
  }
  for (; k<e; ++k){
    uint u = h[(size_t)cw[k]*64 + lane];
    acc.x += bflo(u); acc.y += bfhi(u);
  }
  float dv = dis[i];
  __builtin_nontemporal_store(pack2bf(dv*acc.x, dv*acc.y), &g[(size_t)i*64 + lane]);
}

// ---------- dense via MFMA: hs1 = dis*relu(g @ W1 + b1); A direct from global ----------
__global__ __launch_bounds__(256) void k_mm(const uint* __restrict__ g, const ushort* __restrict__ Wt,
                     const float* __restrict__ b, const float* __restrict__ dis,
                     ushort* __restrict__ h, int n){
  __shared__ uint4 Ws4[2048];   // Wt[128][128] bf16, swizzled, 32KB
  int t = threadIdx.x;
  int n0 = blockIdx.x*64;

  const uint4* Wg = (const uint4*)Wt;
  #pragma unroll
  for (int i=0;i<8;i++){
    int c = t + i*256;
    int row = c>>4, slot = c&15;
    Ws4[row*16 + (slot^(row&7))] = Wg[c];
  }

  int w = t>>6, l = t&63;
  int lr = l&15, lg = l>>4;
  const uint4* Gg = (const uint4*)g;
  size_t arow = (size_t)(n0 + 16*w + lr)*16;
  uint4 a4[4];
  #pragma unroll
  for (int s=0;s<4;s++) a4[s] = Gg[arow + 4*s + lg];   // padded gbuf: safe past n

  __syncthreads();

  f32x4 acc[8];
  #pragma unroll
  for (int j=0;j<8;j++) acc[j] = (f32x4){0.f,0.f,0.f,0.f};

  float bv[8];
  #pragma unroll
  for (int j=0;j<8;j++) bv[j] = b[16*j + lr];

  #pragma unroll
  for (int s=0;s<4;s++){
    short8 a = *(const short8*)&a4[s];
    #pragma unroll
    for (int j=0;j<8;j++){
      short8 bb = *(const short8*)&Ws4[(16*j + lr)*16 + ((4*s + lg)^(lr&7))];
      acc[j] = __builtin_amdgcn_mfma_f32_16x16x32_bf16(a, bb, acc[j], 0, 0, 0);
    }
  }

  #pragma unroll
  for (int j=0;j<8;j++){
    int col = 16*j + lr;
    #pragma unroll
    for (int q=0;q<4;q++){
      int node = n0 + 16*w + lg*4 + q;
      if (node < n){
        float v = dis[node]*fmaxf(acc[j][q] + bv[j], 0.f);
        h[(size_t)node*HDIM + col] = f2bf(v);
      }
    }
  }
}

// ---------- mm2 fused with z: zs = dis*dot(relu(g@W2+b2), Wo); A direct ----------
__global__ __launch_bounds__(256) void k_mmz(const uint* __restrict__ g, const ushort* __restrict__ Wt,
                     const float* __restrict__ b, const float* __restrict__ Wo,
                     const float* __restrict__ dis, float* __restrict__ zs, int n){
  __shared__ uint4 Ws4[2048];
  int t = threadIdx.x;
  int n0 = blockIdx.x*64;

  const uint4* Wg = (const uint4*)Wt;
  #pragma unroll
  for (int i=0;i<8;i++){
    int c = t + i*256;
    int row = c>>4, slot = c&15;
    Ws4[row*16 + (slot^(row&7))] = Wg[c];
  }

  int w = t>>6, l = t&63;
  int lr = l&15, lg = l>>4;
  const uint4* Gg = (const uint4*)g;
  size_t arow = (size_t)(n0 + 16*w + lr)*16;
  uint4 a4[4];
  #pragma unroll
  for (int s=0;s<4;s++) a4[s] = Gg[arow + 4*s + lg];

  __syncthreads();

  f32x4 acc[8];
  #pragma unroll
  for (int j=0;j<8;j++) acc[j] = (f32x4){0.f,0.f,0.f,0.f};

  float bv[8], wo[8];
  #pragma unroll
  for (int j=0;j<8;j++){ bv[j] = b[16*j + lr]; wo[j] = Wo[16*j + lr]; }

  #pragma unroll
  for (int s=0;s<4;s++){
    short8 a = *(const short8*)&a4[s];
    #pragma unroll
    for (int j=0;j<8;j++){
      short8 bb = *(const short8*)&Ws4[(16*j + lr)*16 + ((4*s + lg)^(lr&7))];
      acc[j] = __builtin_amdgcn_mfma_f32_16x16x32_bf16(a, bb, acc[j], 0, 0, 0);
    }
  }

  float zacc[4] = {0.f,0.f,0.f,0.f};
  #pragma unroll
  for (int j=0;j<8;j++){
    #pragma unroll
    for (int q=0;q<4;q++){
      float r = fmaxf(acc[j][q] + bv[j], 0.f);
      zacc[q] = fmaf(r, wo[j], zacc[q]);
    }
  }
  #pragma unroll
  for (int m=1;m<16;m<<=1){
    #pragma unroll
    for (int q=0;q<4;q++) zacc[q] += __shfl_xor(zacc[q], m);
  }
  if (lr==0){
    #pragma unroll
    for (int q=0;q<4;q++){
      int node = n0 + 16*w + lg*4 + q;
      if (node < n) zs[node] = dis[node]*zacc[q];
    }
  }
}

// ---------- y_i = sigmoid(dis_i*(zs_i + sum zs[src]) + bo) ----------
__global__ void k_final(const float* __restrict__ zs, const int* __restrict__ off, const int* __restrict__ cnt,
                        const int* __restrict__ cw, const float* __restrict__ dis,
                        const float* __restrict__ bo, float* __restrict__ y, int n){
  int i = blockIdx.x*256 + threadIdx.x;
  if (i>=n) return;
  int b = off[i], e = b + cnt[i];
  float acc = zs[i];
  int k = b;
  for (; k+4<=e; k+=4){
    int4 s4 = *(const int4*)(cw + k);
    acc += (zs[s4.x]+zs[s4.y]) + (zs[s4.z]+zs[s4.w]);
  }
  for (; k<e; ++k) acc += zs[cw[k]];
  float v = dis[i]*acc + bo[0];
  y[i] = 1.f/(1.f + expf(-v));
}

extern "C" void kernel_launch(void* const* d_in, const int* in_sizes, int n_in,
                              void* d_out, int out_size, void* d_ws, size_t ws_size,
                              hipStream_t stream){
  const float* x  = (const float*)d_in[0];
  const int*   ei = (const int*)d_in[1];
  const float* W0 = (const float*)d_in[2];
  const float* b0 = (const float*)d_in[3];
  const float* W1 = (const float*)d_in[4];
  const float* b1 = (const float*)d_in[5];
  const float* W2 = (const float*)d_in[6];
  const float* b2 = (const float*)d_in[7];
  const float* Wo = (const float*)d_in[8];
  const float* bo = (const float*)d_in[9];
  int n = in_sizes[0];
  int e = in_sizes[1]/2;
  const int* src = ei;
  const int* dst = ei + e;
  float* y = (float*)d_out;

  int R2 = (n + NBUCK-1) / NBUCK;   // nodes per bucket (196 @ n=100k; must be <=256)

  char* p = (char*)d_ws;
  auto alloc = [&](size_t bytes)->void*{ void* r=p; p += (bytes+255)&~(size_t)255; return r; };
  int*    cnt  = (int*)   alloc((size_t)n*4);
  int*    off  = (int*)   alloc((size_t)n*4);
  int*    gcur = (int*)   alloc((size_t)NBUCK*4);
  float*  dis  = (float*) alloc((size_t)n*4);
  float*  xs   = (float*) alloc((size_t)n*4);
  float2* tb   = (float2*)alloc((size_t)n*8);
  float*  zb   = (float*) alloc((size_t)n*4);
  ushort* Wt1  = (ushort*)alloc((size_t)HDIM*HDIM*2);
  ushort* Wt2  = (ushort*)alloc((size_t)HDIM*HDIM*2);
  int*    cw   = (int*)   alloc((size_t)NBUCK*CAP*4 + 256);  // +tail pad for 16-slot overread
  uint*   bins = (uint*)  alloc((size_t)NBUCK*CAP*4);
  uint*   hb1  = (uint*)  alloc((size_t)n*64*4);
  uint*   gbuf = (uint*)  alloc((size_t)(n+64)*64*4);   // +64 rows pad for direct A-loads

  int nb = (n+255)/256;
  int mb = (n+63)/64;

  k_z512 <<<2,256,0,stream>>>(gcur);
  k_bin  <<<BINB,256,0,stream>>>(src,dst,gcur,bins,e,R2);
  k_csr  <<<NBUCK,256,0,stream>>>(bins,gcur,x,W1,W2,Wt1,Wt2,cnt,off,dis,xs,cw,n,R2);

  k_sagg    <<<nb,256,0,stream>>>(xs,dis,off,cnt,cw,tb,n);
  k_wagg1s  <<<(n+3)/4,256,0,stream>>>(tb,off,cnt,cw,W0,b0,gbuf,n);
  k_mm      <<<mb,256,0,stream>>>(gbuf,Wt1,b1,dis,(ushort*)hb1,n);
  k_wagg    <<<(n+3)/4,256,0,stream>>>(hb1,off,cnt,cw,dis,gbuf,n);
  k_mmz     <<<mb,256,0,stream>>>(gbuf,Wt2,b2,Wo,dis,zb,n);
  k_final   <<<nb,256,0,stream>>>(zb,off,cnt,cw,dis,bo,y,n);
}

// Round 16
// 228.919 us; speedup vs baseline: 1.2420x; 1.2420x over previous
//
#include <hip/hip_runtime.h>
#include <math.h>

#define HDIM 128
#define NBUCK 512   // dst buckets; R2 = ceil(n/512) must be <= 256
#define BINB 128    // blocks in binning grid
#define CH 8192     // edges staged per chunk in k_bin
#define CAP 4096    // bin/cw capacity per bucket (mean 3136, +17 sigma; mult of 4)

typedef unsigned int uint;
typedef unsigned short ushort;
typedef unsigned long long ull;
typedef __attribute__((ext_vector_type(8))) short short8;
typedef __attribute__((ext_vector_type(4))) float f32x4;

// bf16 helpers (bit-level; bf16->fp32 exact, fp32->bf16 RNE)
__device__ __forceinline__ float bflo(uint u){ return __uint_as_float(u<<16); }
__device__ __forceinline__ float bfhi(uint u){ return __uint_as_float(u&0xffff0000u); }
__device__ __forceinline__ ushort f2bf(float f){
  uint x = __float_as_uint(f);
  return (ushort)((x + 0x7fffu + ((x>>16)&1u)) >> 16);
}
__device__ __forceinline__ uint pack2bf(float a, float b){
  return (uint)f2bf(a) | ((uint)f2bf(b)<<16);
}

// ---------- zero the 512 bucket cursors ----------
__global__ void k_z512(int* gcur){
  int i = blockIdx.x*256 + threadIdx.x;
  if (i < NBUCK) gcur[i] = 0;
}

// ---------- single-pass chunked binning ----------
__global__ __launch_bounds__(256) void k_bin(const int* __restrict__ src, const int* __restrict__ dst,
                      int* __restrict__ gcur, uint* __restrict__ bins, int e, int R2){
  __shared__ uint   recs[CH];    // 32KB
  __shared__ ushort qarr[CH];    // 16KB
  __shared__ int    hist[NBUCK]; // 2KB
  __shared__ int    base[NBUCK]; // 2KB
  int t = threadIdx.x;
  int nch = (e + CH - 1)/CH;
  for (int c = blockIdx.x; c < nch; c += gridDim.x){
    int c0 = c*CH;
    int m = min(e - c0, CH);
    for (int u=t; u<NBUCK; u+=256) hist[u]=0;
    __syncthreads();
    for (int j=t; j<m; j+=256){
      int s = __builtin_nontemporal_load(&src[c0+j]);
      int d = __builtin_nontemporal_load(&dst[c0+j]);
      int q = d / R2;
      recs[j] = ((uint)s<<8) | (uint)(d - q*R2);
      qarr[j] = (ushort)q;
      atomicAdd(&hist[q],1);
    }
    __syncthreads();
    for (int u=t; u<NBUCK; u+=256){
      int cn = hist[u];
      base[u] = cn ? atomicAdd(&gcur[u], cn) : 0;
      hist[u] = 0;                       // reuse as placement cursor
    }
    __syncthreads();
    for (int j=t; j<m; j+=256){
      int q = qarr[j];
      int lp = base[q] + atomicAdd(&hist[q],1);
      if (lp < CAP) bins[q*CAP + lp] = recs[j];
    }
    __syncthreads();
  }
}

// ---------- per-bucket CSR build (block-local) + W transpose fold-in ----------
__global__ __launch_bounds__(256) void k_csr(const uint* __restrict__ bins, const int* __restrict__ gcur,
                      const float* __restrict__ x,
                      const float* __restrict__ W1, const float* __restrict__ W2,
                      ushort* __restrict__ Wt1, ushort* __restrict__ Wt2,
                      int* __restrict__ cnt, int* __restrict__ off,
                      float* __restrict__ dis, float* __restrict__ xs, int* __restrict__ cw,
                      int n, int R2){
  __shared__ uint recs[CAP];     // 16KB
  __shared__ int lcnt[256];
  __shared__ int lofs[256];
  __shared__ int tmp[256];
  int q = blockIdx.x;
  int t = threadIdx.x;
  if (q < 64){                   // Wt transpose: 64 blocks x 256 = 16384 entries
    int i = q*256 + t;
    int no = i>>7, k = i&127;
    Wt1[i] = f2bf(W1[k*HDIM+no]);
    Wt2[i] = f2bf(W2[k*HDIM+no]);
  }
  int d0 = q*R2;
  int nloc = min(n - d0, R2);
  if (nloc <= 0) return;
  int estart = q*CAP;
  int m = min(gcur[q], CAP);
  lcnt[t] = 0;
  for (int i = t; i < m; i += 256) recs[i] = bins[estart+i];
  __syncthreads();
  for (int i = t; i < m; i += 256) atomicAdd(&lcnt[recs[i] & 255u], 1);
  __syncthreads();
  int v = (t<nloc) ? lcnt[t] : 0;
  int span = (v+3)&~3;           // 16B-aligned per-node segment
  tmp[t] = span; __syncthreads();
  for (int d=1; d<256; d<<=1){
    int a = (t>=d) ? tmp[t-d] : 0;
    __syncthreads(); tmp[t] += a; __syncthreads();
  }
  int excl = tmp[t] - span;
  if (t<nloc){
    int node = d0 + t;
    cnt[node] = v;
    off[node] = estart + excl;
    float dv = rsqrtf((float)(v+1));
    dis[node] = dv;
    xs[node] = dv*x[node];
    lofs[t] = excl;
    lcnt[t] = 0;                 // reuse as cursor
  }
  __syncthreads();
  for (int i = t; i < m; i += 256){
    uint r = recs[i];
    int dl = r & 255u;
    int pos = estart + lofs[dl] + atomicAdd(&lcnt[dl], 1);
    cw[pos] = (int)(r >> 8);
  }
}

// ---------- scalar aggregation -> tb[i] = pack2bf(s_i, dis_i) ----------
__global__ void k_sagg(const float* __restrict__ xs, const float* __restrict__ dis,
                       const int* __restrict__ off, const int* __restrict__ cnt,
                       const int* __restrict__ cw, uint* __restrict__ tb, int n){
  int i = blockIdx.x*256 + threadIdx.x;
  if (i>=n) return;
  int b = off[i], e = b + cnt[i];
  float acc = xs[i];
  int k = b;
  for (; k+4<=e; k+=4){
    int4 s4 = *(const int4*)(cw + k);
    acc += (xs[s4.x]+xs[s4.y]) + (xs[s4.z]+xs[s4.w]);
  }
  for (; k<e; ++k) acc += xs[cw[k]];
  float dv = dis[i];
  tb[i] = pack2bf(dv*acc, dv);
}

// ---------- layer-1 aggregation via rank-1 reconstruction, lane-batched ----------
// (s_j, dis_j) packed as 2xbf16 in one word -> ONE shfl per edge (was two).
// Lanes 0-15 load 16 edges' packed scalars in one per-lane load.
__global__ __launch_bounds__(256) void k_wagg1s(const uint* __restrict__ tb, const int* __restrict__ off,
                       const int* __restrict__ cnt, const int* __restrict__ cw,
                       const float* __restrict__ W0, const float* __restrict__ b0,
                       uint* __restrict__ g, int n){
  int wave = threadIdx.x>>6, lane = threadIdx.x&63;
  int i = blockIdx.x*4 + wave;
  if (i>=n) return;
  float2 w0 = ((const float2*)W0)[lane];
  float2 b0v = ((const float2*)b0)[lane];
  int b = off[i], e = b + cnt[i];
  uint ui = tb[i];
  float si = bflo(ui), di = bfhi(ui);
  float2 acc;
  acc.x = di * fmaxf(fmaf(si, w0.x, b0v.x), 0.f);
  acc.y = di * fmaxf(fmaf(si, w0.y, b0v.y), 0.f);
  int l16 = lane & 15;
  int k = b;
  int efull = b + ((e - b) & ~15);
  for (; k < efull; k += 16){          // full batches: 1 load + 16 shfl per 16 edges
    uint tt = tb[cw[k + l16]];
    #pragma unroll
    for (int j=0;j<16;j++){
      uint u = (uint)__shfl((int)tt, j);
      float sj = bflo(u), dj = bfhi(u);
      acc.x = fmaf(dj, fmaxf(fmaf(sj, w0.x, b0v.x), 0.f), acc.x);
      acc.y = fmaf(dj, fmaxf(fmaf(sj, w0.y, b0v.y), 0.f), acc.y);
    }
  }
  int rem = e - k;                     // wave-uniform remainder 0..15
  if (rem > 0){
    bool ok = l16 < rem;
    int ci = ok ? cw[k + l16] : 0;
    uint tt = tb[ci];
    for (int j=0;j<rem;j++){           // uniform dynamic bound
      uint u = (uint)__shfl((int)tt, j);
      float sj = bflo(u), dj = bfhi(u);
      acc.x = fmaf(dj, fmaxf(fmaf(sj, w0.x, b0v.x), 0.f), acc.x);
      acc.y = fmaf(dj, fmaxf(fmaf(sj, w0.y, b0v.y), 0.f), acc.y);
    }
  }
  __builtin_nontemporal_store(pack2bf(di*acc.x, di*acc.y), &g[(size_t)i*64 + lane]);
}

// ---------- wide aggregation: g_i = dis_i*(hs_i + sum hs[src]); int4 cw loads ----------
__global__ __launch_bounds__(256) void k_wagg(const uint* __restrict__ h, const int* __restrict__ off,
                       const int* __restrict__ cnt, const int* __restrict__ cw,
                       const float* __restrict__ dis, uint* __restrict__ g, int n){
  int wave = threadIdx.x>>6, lane = threadIdx.x&63;
  int i = blockIdx.x*4 + wave;
  if (i>=n) return;
  int b = off[i], e = b + cnt[i];
  uint su = h[(size_t)i*64 + lane];
  float2 acc; acc.x = bflo(su); acc.y = bfhi(su);
  int k = b;
  for (; k+16<=e; k+=16){
    const int4* c4 = (const int4*)(cw + k);   // b is 16B-aligned
    int4 v0 = c4[0], v1 = c4[1], v2 = c4[2], v3 = c4[3];
    int v[16] = {v0.x,v0.y,v0.z,v0.w, v1.x,v1.y,v1.z,v1.w,
                 v2.x,v2.y,v2.z,v2.w, v3.x,v3.y,v3.z,v3.w};
    uint u[16];
    #pragma unroll
    for (int j=0;j<16;j++) u[j] = h[(size_t)v[j]*64 + lane];
    #pragma unroll
    for (int j=0;j<16;j++){ acc.x += bflo(u[j]); acc.y += bfhi(u[j]); }
  }
  for (; k+4<=e; k+=4){
    int4 v4 = *(const int4*)(cw + k);
    uint u0 = h[(size_t)v4.x*64 + lane];
    uint u1 = h[(size_t)v4.y*64 + lane];
    uint u2 = h[(size_t)v4.z*64 + lane];
    uint u3 = h[(size_t)v4.w*64 + lane];
    acc.x += bflo(u0)+bflo(u1)+bflo(u2)+bflo(u3);
    acc.y += bfhi(u0)+bfhi(u1)+bfhi(u2)+bfhi(u3);
  }
  for (; k<e; ++k){
    uint u = h[(size_t)cw[k]*64 + lane];
    acc.x += bflo(u); acc.y += bfhi(u);
  }
  float dv = dis[i];
  __builtin_nontemporal_store(pack2bf(dv*acc.x, dv*acc.y), &g[(size_t)i*64 + lane]);
}

// ---------- dense via MFMA: hs1 = dis*relu(g @ W1 + b1); A direct from global ----------
__global__ __launch_bounds__(256) void k_mm(const uint* __restrict__ g, const ushort* __restrict__ Wt,
                     const float* __restrict__ b, const float* __restrict__ dis,
                     ushort* __restrict__ h, int n){
  __shared__ uint4 Ws4[2048];   // Wt[128][128] bf16, swizzled, 32KB
  int t = threadIdx.x;
  int n0 = blockIdx.x*64;

  const uint4* Wg = (const uint4*)Wt;
  #pragma unroll
  for (int i=0;i<8;i++){
    int c = t + i*256;
    int row = c>>4, slot = c&15;
    Ws4[row*16 + (slot^(row&7))] = Wg[c];
  }

  int w = t>>6, l = t&63;
  int lr = l&15, lg = l>>4;
  const uint4* Gg = (const uint4*)g;
  size_t arow = (size_t)(n0 + 16*w + lr)*16;
  uint4 a4[4];
  #pragma unroll
  for (int s=0;s<4;s++) a4[s] = Gg[arow + 4*s + lg];   // padded gbuf: safe past n

  __syncthreads();

  f32x4 acc[8];
  #pragma unroll
  for (int j=0;j<8;j++) acc[j] = (f32x4){0.f,0.f,0.f,0.f};

  float bv[8];
  #pragma unroll
  for (int j=0;j<8;j++) bv[j] = b[16*j + lr];

  #pragma unroll
  for (int s=0;s<4;s++){
    short8 a = *(const short8*)&a4[s];
    #pragma unroll
    for (int j=0;j<8;j++){
      short8 bb = *(const short8*)&Ws4[(16*j + lr)*16 + ((4*s + lg)^(lr&7))];
      acc[j] = __builtin_amdgcn_mfma_f32_16x16x32_bf16(a, bb, acc[j], 0, 0, 0);
    }
  }

  #pragma unroll
  for (int j=0;j<8;j++){
    int col = 16*j + lr;
    #pragma unroll
    for (int q=0;q<4;q++){
      int node = n0 + 16*w + lg*4 + q;
      if (node < n){
        float v = dis[node]*fmaxf(acc[j][q] + bv[j], 0.f);
        h[(size_t)node*HDIM + col] = f2bf(v);
      }
    }
  }
}

// ---------- mm2 fused with z: zs = dis*dot(relu(g@W2+b2), Wo); A direct ----------
__global__ __launch_bounds__(256) void k_mmz(const uint* __restrict__ g, const ushort* __restrict__ Wt,
                     const float* __restrict__ b, const float* __restrict__ Wo,
                     const float* __restrict__ dis, float* __restrict__ zs, int n){
  __shared__ uint4 Ws4[2048];
  int t = threadIdx.x;
  int n0 = blockIdx.x*64;

  const uint4* Wg = (const uint4*)Wt;
  #pragma unroll
  for (int i=0;i<8;i++){
    int c = t + i*256;
    int row = c>>4, slot = c&15;
    Ws4[row*16 + (slot^(row&7))] = Wg[c];
  }

  int w = t>>6, l = t&63;
  int lr = l&15, lg = l>>4;
  const uint4* Gg = (const uint4*)g;
  size_t arow = (size_t)(n0 + 16*w + lr)*16;
  uint4 a4[4];
  #pragma unroll
  for (int s=0;s<4;s++) a4[s] = Gg[arow + 4*s + lg];

  __syncthreads();

  f32x4 acc[8];
  #pragma unroll
  for (int j=0;j<8;j++) acc[j] = (f32x4){0.f,0.f,0.f,0.f};

  float bv[8], wo[8];
  #pragma unroll
  for (int j=0;j<8;j++){ bv[j] = b[16*j + lr]; wo[j] = Wo[16*j + lr]; }

  #pragma unroll
  for (int s=0;s<4;s++){
    short8 a = *(const short8*)&a4[s];
    #pragma unroll
    for (int j=0;j<8;j++){
      short8 bb = *(const short8*)&Ws4[(16*j + lr)*16 + ((4*s + lg)^(lr&7))];
      acc[j] = __builtin_amdgcn_mfma_f32_16x16x32_bf16(a, bb, acc[j], 0, 0, 0);
    }
  }

  float zacc[4] = {0.f,0.f,0.f,0.f};
  #pragma unroll
  for (int j=0;j<8;j++){
    #pragma unroll
    for (int q=0;q<4;q++){
      float r = fmaxf(acc[j][q] + bv[j], 0.f);
      zacc[q] = fmaf(r, wo[j], zacc[q]);
    }
  }
  #pragma unroll
  for (int m=1;m<16;m<<=1){
    #pragma unroll
    for (int q=0;q<4;q++) zacc[q] += __shfl_xor(zacc[q], m);
  }
  if (lr==0){
    #pragma unroll
    for (int q=0;q<4;q++){
      int node = n0 + 16*w + lg*4 + q;
      if (node < n) zs[node] = dis[node]*zacc[q];
    }
  }
}

// ---------- y_i = sigmoid(dis_i*(zs_i + sum zs[src]) + bo) ----------
__global__ void k_final(const float* __restrict__ zs, const int* __restrict__ off, const int* __restrict__ cnt,
                        const int* __restrict__ cw, const float* __restrict__ dis,
                        const float* __restrict__ bo, float* __restrict__ y, int n){
  int i = blockIdx.x*256 + threadIdx.x;
  if (i>=n) return;
  int b = off[i], e = b + cnt[i];
  float acc = zs[i];
  int k = b;
  for (; k+4<=e; k+=4){
    int4 s4 = *(const int4*)(cw + k);
    acc += (zs[s4.x]+zs[s4.y]) + (zs[s4.z]+zs[s4.w]);
  }
  for (; k<e; ++k) acc += zs[cw[k]];
  float v = dis[i]*acc + bo[0];
  y[i] = 1.f/(1.f + expf(-v));
}

extern "C" void kernel_launch(void* const* d_in, const int* in_sizes, int n_in,
                              void* d_out, int out_size, void* d_ws, size_t ws_size,
                              hipStream_t stream){
  const float* x  = (const float*)d_in[0];
  const int*   ei = (const int*)d_in[1];
  const float* W0 = (const float*)d_in[2];
  const float* b0 = (const float*)d_in[3];
  const float* W1 = (const float*)d_in[4];
  const float* b1 = (const float*)d_in[5];
  const float* W2 = (const float*)d_in[6];
  const float* b2 = (const float*)d_in[7];
  const float* Wo = (const float*)d_in[8];
  const float* bo = (const float*)d_in[9];
  int n = in_sizes[0];
  int e = in_sizes[1]/2;
  const int* src = ei;
  const int* dst = ei + e;
  float* y = (float*)d_out;

  int R2 = (n + NBUCK-1) / NBUCK;   // nodes per bucket (196 @ n=100k; must be <=256)

  char* p = (char*)d_ws;
  auto alloc = [&](size_t bytes)->void*{ void* r=p; p += (bytes+255)&~(size_t)255; return r; };
  int*    cnt  = (int*)   alloc((size_t)n*4);
  int*    off  = (int*)   alloc((size_t)n*4);
  int*    gcur = (int*)   alloc((size_t)NBUCK*4);
  float*  dis  = (float*) alloc((size_t)n*4);
  float*  xs   = (float*) alloc((size_t)n*4);
  uint*   tb   = (uint*)  alloc((size_t)n*4);
  float*  zb   = (float*) alloc((size_t)n*4);
  ushort* Wt1  = (ushort*)alloc((size_t)HDIM*HDIM*2);
  ushort* Wt2  = (ushort*)alloc((size_t)HDIM*HDIM*2);
  int*    cw   = (int*)   alloc((size_t)NBUCK*CAP*4 + 256);  // +tail pad for overread
  uint*   bins = (uint*)  alloc((size_t)NBUCK*CAP*4);
  uint*   hb1  = (uint*)  alloc((size_t)n*64*4);
  uint*   gbuf = (uint*)  alloc((size_t)(n+64)*64*4);   // +64 rows pad for direct A-loads

  int nb = (n+255)/256;
  int mb = (n+63)/64;

  k_z512 <<<2,256,0,stream>>>(gcur);
  k_bin  <<<BINB,256,0,stream>>>(src,dst,gcur,bins,e,R2);
  k_csr  <<<NBUCK,256,0,stream>>>(bins,gcur,x,W1,W2,Wt1,Wt2,cnt,off,dis,xs,cw,n,R2);

  k_sagg    <<<nb,256,0,stream>>>(xs,dis,off,cnt,cw,tb,n);
  k_wagg1s  <<<(n+3)/4,256,0,stream>>>(tb,off,cnt,cw,W0,b0,gbuf,n);
  k_mm      <<<mb,256,0,stream>>>(gbuf,Wt1,b1,dis,(ushort*)hb1,n);
  k_wagg    <<<(n+3)/4,256,0,stream>>>(hb1,off,cnt,cw,dis,gbuf,n);
  k_mmz     <<<mb,256,0,stream>>>(gbuf,Wt2,b2,Wo,dis,zb,n);
  k_final   <<<nb,256,0,stream>>>(zb,off,cnt,cw,dis,bo,y,n);
}

// Round 17
// 215.445 us; speedup vs baseline: 1.3197x; 1.0625x over previous
//
#include <hip/hip_runtime.h>
#include <math.h>

#define HDIM 128
#define NBUCK 512   // dst buckets; R2 = ceil(n/512) must be <= 256
#define BINB 256    // blocks in binning grid (>= nch so each block owns <=1 chunk)
#define CH 8192     // edges staged per chunk in k_bin
#define RECCAP 4096 // bin capacity per bucket (records; mean ~3136, +17 sigma)
#define CWCAP 8192  // cw capacity per bucket (16-padded segments; bound m+15*256 < 8192)

typedef unsigned int uint;
typedef unsigned short ushort;
typedef unsigned long long ull;
typedef __attribute__((ext_vector_type(8))) short short8;
typedef __attribute__((ext_vector_type(4))) float f32x4;

// bf16 helpers (bit-level; bf16->fp32 exact, fp32->bf16 RNE)
__device__ __forceinline__ float bflo(uint u){ return __uint_as_float(u<<16); }
__device__ __forceinline__ float bfhi(uint u){ return __uint_as_float(u&0xffff0000u); }
__device__ __forceinline__ ushort f2bf(float f){
  uint x = __float_as_uint(f);
  return (ushort)((x + 0x7fffu + ((x>>16)&1u)) >> 16);
}
__device__ __forceinline__ uint pack2bf(float a, float b){
  return (uint)f2bf(a) | ((uint)f2bf(b)<<16);
}

// ---------- zero the 512 bucket cursors ----------
__global__ void k_z512(int* gcur){
  int i = blockIdx.x*256 + threadIdx.x;
  if (i < NBUCK) gcur[i] = 0;
}

// ---------- single-pass chunked binning ----------
__global__ __launch_bounds__(256) void k_bin(const int* __restrict__ src, const int* __restrict__ dst,
                      int* __restrict__ gcur, uint* __restrict__ bins, int e, int R2){
  __shared__ uint   recs[CH];    // 32KB
  __shared__ ushort qarr[CH];    // 16KB
  __shared__ int    hist[NBUCK]; // 2KB
  __shared__ int    base[NBUCK]; // 2KB
  int t = threadIdx.x;
  int nch = (e + CH - 1)/CH;
  for (int c = blockIdx.x; c < nch; c += gridDim.x){
    int c0 = c*CH;
    int m = min(e - c0, CH);
    for (int u=t; u<NBUCK; u+=256) hist[u]=0;
    __syncthreads();
    for (int j=t; j<m; j+=256){
      int s = __builtin_nontemporal_load(&src[c0+j]);
      int d = __builtin_nontemporal_load(&dst[c0+j]);
      int q = d / R2;
      recs[j] = ((uint)s<<8) | (uint)(d - q*R2);
      qarr[j] = (ushort)q;
      atomicAdd(&hist[q],1);
    }
    __syncthreads();
    for (int u=t; u<NBUCK; u+=256){
      int cn = hist[u];
      base[u] = cn ? atomicAdd(&gcur[u], cn) : 0;
      hist[u] = 0;                       // reuse as placement cursor
    }
    __syncthreads();
    for (int j=t; j<m; j+=256){
      int q = qarr[j];
      int lp = base[q] + atomicAdd(&hist[q],1);
      if (lp < RECCAP) bins[q*RECCAP + lp] = recs[j];
    }
    __syncthreads();
  }
}

// ---------- per-bucket CSR build (block-local) + W transpose fold-in ----------
// Per-node cw segments padded to 16-record multiples with sentinel index n
// (tb[n]=0 -> pad contribution is exactly +0.0 in wagg1s).
__global__ __launch_bounds__(256) void k_csr(const uint* __restrict__ bins, const int* __restrict__ gcur,
                      const float* __restrict__ x,
                      const float* __restrict__ W1, const float* __restrict__ W2,
                      ushort* __restrict__ Wt1, ushort* __restrict__ Wt2,
                      int* __restrict__ cnt, int* __restrict__ off,
                      float* __restrict__ dis, float* __restrict__ xs, int* __restrict__ cw,
                      int n, int R2){
  __shared__ uint recs[RECCAP];  // 16KB
  __shared__ int lcnt[256];
  __shared__ int lofs[256];
  __shared__ int tmp[256];
  int q = blockIdx.x;
  int t = threadIdx.x;
  if (q < 64){                   // Wt transpose: 64 blocks x 256 = 16384 entries
    int i = q*256 + t;
    int no = i>>7, k = i&127;
    Wt1[i] = f2bf(W1[k*HDIM+no]);
    Wt2[i] = f2bf(W2[k*HDIM+no]);
  }
  int d0 = q*R2;
  int nloc = min(n - d0, R2);
  if (nloc <= 0) return;
  int estart = q*CWCAP;          // padded cw segment base
  int m = min(gcur[q], RECCAP);
  lcnt[t] = 0;
  for (int i = t; i < m; i += 256) recs[i] = bins[(size_t)q*RECCAP + i];
  __syncthreads();
  for (int i = t; i < m; i += 256) atomicAdd(&lcnt[recs[i] & 255u], 1);
  __syncthreads();
  int v = (t<nloc) ? lcnt[t] : 0;
  int span = (v+15)&~15;         // 16-record aligned per-node segment
  tmp[t] = span; __syncthreads();
  for (int d=1; d<256; d<<=1){
    int a = (t>=d) ? tmp[t-d] : 0;
    __syncthreads(); tmp[t] += a; __syncthreads();
  }
  int excl = tmp[t] - span;
  if (t<nloc){
    int node = d0 + t;
    cnt[node] = v;
    off[node] = estart + excl;
    float dv = rsqrtf((float)(v+1));
    dis[node] = dv;
    xs[node] = dv*x[node];
    lofs[t] = excl;
    lcnt[t] = 0;                 // reuse as cursor
  }
  __syncthreads();
  for (int i = t; i < m; i += 256){
    uint r = recs[i];
    int dl = r & 255u;
    int pos = estart + lofs[dl] + atomicAdd(&lcnt[dl], 1);
    cw[pos] = (int)(r >> 8);
  }
  // fill pad slots with sentinel n (no sync needed: disjoint slots)
  if (t<nloc){
    int basep = estart + lofs[t];
    for (int j = v; j < span; ++j) cw[basep + j] = n;
  }
}

// ---------- scalar aggregation -> tb[i] = pack2bf(s_i, dis_i); tb[n]=0 sentinel ----------
__global__ void k_sagg(const float* __restrict__ xs, const float* __restrict__ dis,
                       const int* __restrict__ off, const int* __restrict__ cnt,
                       const int* __restrict__ cw, uint* __restrict__ tb, int n){
  int i = blockIdx.x*256 + threadIdx.x;
  if (i>n) return;
  if (i==n){ tb[n] = 0u; return; }     // sentinel: s=0, dis=0
  int b = off[i], e = b + cnt[i];
  float acc = xs[i];
  int k = b;
  for (; k+4<=e; k+=4){
    int4 s4 = *(const int4*)(cw + k);
    acc += (xs[s4.x]+xs[s4.y]) + (xs[s4.z]+xs[s4.w]);
  }
  for (; k<e; ++k) acc += xs[cw[k]];
  float dv = dis[i];
  tb[i] = pack2bf(dv*acc, dv);
}

// ---------- layer-1 aggregation via rank-1 reconstruction ----------
// Fully-unrolled 16-edge batches over the padded segment: 1 per-lane load +
// 16 shfl per batch, zero predicates/tail (pads hit tb[n]=0 -> +0.0 exact).
__global__ __launch_bounds__(256) void k_wagg1s(const uint* __restrict__ tb, const int* __restrict__ off,
                       const int* __restrict__ cnt, const int* __restrict__ cw,
                       const float* __restrict__ W0, const float* __restrict__ b0,
                       uint* __restrict__ g, int n){
  int wave = threadIdx.x>>6, lane = threadIdx.x&63;
  int i = blockIdx.x*4 + wave;
  if (i>=n) return;
  float2 w0 = ((const float2*)W0)[lane];
  float2 b0v = ((const float2*)b0)[lane];
  int b = off[i];
  int e16 = b + ((cnt[i]+15)&~15);
  uint ui = tb[i];
  float si = bflo(ui), di = bfhi(ui);
  float2 acc;
  acc.x = di * fmaxf(fmaf(si, w0.x, b0v.x), 0.f);
  acc.y = di * fmaxf(fmaf(si, w0.y, b0v.y), 0.f);
  int l16 = lane & 15;
  for (int k = b; k < e16; k += 16){
    uint tt = tb[cw[k + l16]];
    #pragma unroll
    for (int j=0;j<16;j++){
      uint u = (uint)__shfl((int)tt, j);
      float sj = bflo(u), dj = bfhi(u);
      acc.x = fmaf(dj, fmaxf(fmaf(sj, w0.x, b0v.x), 0.f), acc.x);
      acc.y = fmaf(dj, fmaxf(fmaf(sj, w0.y, b0v.y), 0.f), acc.y);
    }
  }
  __builtin_nontemporal_store(pack2bf(di*acc.x, di*acc.y), &g[(size_t)i*64 + lane]);
}

// ---------- wide aggregation: g_i = dis_i*(hs_i + sum hs[src]); exact cnt ----------
__global__ __launch_bounds__(256) void k_wagg(const uint* __restrict__ h, const int* __restrict__ off,
                       const int* __restrict__ cnt, const int* __restrict__ cw,
                       const float* __restrict__ dis, uint* __restrict__ g, int n){
  int wave = threadIdx.x>>6, lane = threadIdx.x&63;
  int i = blockIdx.x*4 + wave;
  if (i>=n) return;
  int b = off[i], e = b + cnt[i];
  uint su = h[(size_t)i*64 + lane];
  float2 acc; acc.x = bflo(su); acc.y = bfhi(su);
  int k = b;
  for (; k+16<=e; k+=16){
    const int4* c4 = (const int4*)(cw + k);   // b is 16-element aligned
    int4 v0 = c4[0], v1 = c4[1], v2 = c4[2], v3 = c4[3];
    int v[16] = {v0.x,v0.y,v0.z,v0.w, v1.x,v1.y,v1.z,v1.w,
                 v2.x,v2.y,v2.z,v2.w, v3.x,v3.y,v3.z,v3.w};
    uint u[16];
    #pragma unroll
    for (int j=0;j<16;j++) u[j] = h[(size_t)v[j]*64 + lane];
    #pragma unroll
    for (int j=0;j<16;j++){ acc.x += bflo(u[j]); acc.y += bfhi(u[j]); }
  }
  for (; k+4<=e; k+=4){
    int4 v4 = *(const int4*)(cw + k);
    uint u0 = h[(size_t)v4.x*64 + lane];
    uint u1 = h[(size_t)v4.y*64 + lane];
    uint u2 = h[(size_t)v4.z*64 + lane];
    uint u3 = h[(size_t)v4.w*64 + lane];
    acc.x += bflo(u0)+bflo(u1)+bflo(u2)+bflo(u3);
    acc.y += bfhi(u0)+bfhi(u1)+bfhi(u2)+bfhi(u3);
  }
  for (; k<e; ++k){
    uint u = h[(size_t)cw[k]*64 + lane];
    acc.x += bflo(u); acc.y += bfhi(u);
  }
  float dv = dis[i];
  __builtin_nontemporal_store(pack2bf(dv*acc.x, dv*acc.y), &g[(size_t)i*64 + lane]);
}

// ---------- dense via MFMA: hs1 = dis*relu(g @ W1 + b1); A direct from global ----------
__global__ __launch_bounds__(256) void k_mm(const uint* __restrict__ g, const ushort* __restrict__ Wt,
                     const float* __restrict__ b, const float* __restrict__ dis,
                     ushort* __restrict__ h, int n){
  __shared__ uint4 Ws4[2048];   // Wt[128][128] bf16, swizzled, 32KB
  int t = threadIdx.x;
  int n0 = blockIdx.x*64;

  const uint4* Wg = (const uint4*)Wt;
  #pragma unroll
  for (int i=0;i<8;i++){
    int c = t + i*256;
    int row = c>>4, slot = c&15;
    Ws4[row*16 + (slot^(row&7))] = Wg[c];
  }

  int w = t>>6, l = t&63;
  int lr = l&15, lg = l>>4;
  const uint4* Gg = (const uint4*)g;
  size_t arow = (size_t)(n0 + 16*w + lr)*16;
  uint4 a4[4];
  #pragma unroll
  for (int s=0;s<4;s++) a4[s] = Gg[arow + 4*s + lg];   // padded gbuf: safe past n

  __syncthreads();

  f32x4 acc[8];
  #pragma unroll
  for (int j=0;j<8;j++) acc[j] = (f32x4){0.f,0.f,0.f,0.f};

  float bv[8];
  #pragma unroll
  for (int j=0;j<8;j++) bv[j] = b[16*j + lr];

  #pragma unroll
  for (int s=0;s<4;s++){
    short8 a = *(const short8*)&a4[s];
    #pragma unroll
    for (int j=0;j<8;j++){
      short8 bb = *(const short8*)&Ws4[(16*j + lr)*16 + ((4*s + lg)^(lr&7))];
      acc[j] = __builtin_amdgcn_mfma_f32_16x16x32_bf16(a, bb, acc[j], 0, 0, 0);
    }
  }

  #pragma unroll
  for (int j=0;j<8;j++){
    int col = 16*j + lr;
    #pragma unroll
    for (int q=0;q<4;q++){
      int node = n0 + 16*w + lg*4 + q;
      if (node < n){
        float v = dis[node]*fmaxf(acc[j][q] + bv[j], 0.f);
        h[(size_t)node*HDIM + col] = f2bf(v);
      }
    }
  }
}

// ---------- mm2 fused with z: zs = dis*dot(relu(g@W2+b2), Wo); A direct ----------
__global__ __launch_bounds__(256) void k_mmz(const uint* __restrict__ g, const ushort* __restrict__ Wt,
                     const float* __restrict__ b, const float* __restrict__ Wo,
                     const float* __restrict__ dis, float* __restrict__ zs, int n){
  __shared__ uint4 Ws4[2048];
  int t = threadIdx.x;
  int n0 = blockIdx.x*64;

  const uint4* Wg = (const uint4*)Wt;
  #pragma unroll
  for (int i=0;i<8;i++){
    int c = t + i*256;
    int row = c>>4, slot = c&15;
    Ws4[row*16 + (slot^(row&7))] = Wg[c];
  }

  int w = t>>6, l = t&63;
  int lr = l&15, lg = l>>4;
  const uint4* Gg = (const uint4*)g;
  size_t arow = (size_t)(n0 + 16*w + lr)*16;
  uint4 a4[4];
  #pragma unroll
  for (int s=0;s<4;s++) a4[s] = Gg[arow + 4*s + lg];

  __syncthreads();

  f32x4 acc[8];
  #pragma unroll
  for (int j=0;j<8;j++) acc[j] = (f32x4){0.f,0.f,0.f,0.f};

  float bv[8], wo[8];
  #pragma unroll
  for (int j=0;j<8;j++){ bv[j] = b[16*j + lr]; wo[j] = Wo[16*j + lr]; }

  #pragma unroll
  for (int s=0;s<4;s++){
    short8 a = *(const short8*)&a4[s];
    #pragma unroll
    for (int j=0;j<8;j++){
      short8 bb = *(const short8*)&Ws4[(16*j + lr)*16 + ((4*s + lg)^(lr&7))];
      acc[j] = __builtin_amdgcn_mfma_f32_16x16x32_bf16(a, bb, acc[j], 0, 0, 0);
    }
  }

  float zacc[4] = {0.f,0.f,0.f,0.f};
  #pragma unroll
  for (int j=0;j<8;j++){
    #pragma unroll
    for (int q=0;q<4;q++){
      float r = fmaxf(acc[j][q] + bv[j], 0.f);
      zacc[q] = fmaf(r, wo[j], zacc[q]);
    }
  }
  #pragma unroll
  for (int m=1;m<16;m<<=1){
    #pragma unroll
    for (int q=0;q<4;q++) zacc[q] += __shfl_xor(zacc[q], m);
  }
  if (lr==0){
    #pragma unroll
    for (int q=0;q<4;q++){
      int node = n0 + 16*w + lg*4 + q;
      if (node < n) zs[node] = dis[node]*zacc[q];
    }
  }
}

// ---------- y_i = sigmoid(dis_i*(zs_i + sum zs[src]) + bo) ----------
__global__ void k_final(const float* __restrict__ zs, const int* __restrict__ off, const int* __restrict__ cnt,
                        const int* __restrict__ cw, const float* __restrict__ dis,
                        const float* __restrict__ bo, float* __restrict__ y, int n){
  int i = blockIdx.x*256 + threadIdx.x;
  if (i>=n) return;
  int b = off[i], e = b + cnt[i];
  float acc = zs[i];
  int k = b;
  for (; k+4<=e; k+=4){
    int4 s4 = *(const int4*)(cw + k);
    acc += (zs[s4.x]+zs[s4.y]) + (zs[s4.z]+zs[s4.w]);
  }
  for (; k<e; ++k) acc += zs[cw[k]];
  float v = dis[i]*acc + bo[0];
  y[i] = 1.f/(1.f + expf(-v));
}

extern "C" void kernel_launch(void* const* d_in, const int* in_sizes, int n_in,
                              void* d_out, int out_size, void* d_ws, size_t ws_size,
                              hipStream_t stream){
  const float* x  = (const float*)d_in[0];
  const int*   ei = (const int*)d_in[1];
  const float* W0 = (const float*)d_in[2];
  const float* b0 = (const float*)d_in[3];
  const float* W1 = (const float*)d_in[4];
  const float* b1 = (const float*)d_in[5];
  const float* W2 = (const float*)d_in[6];
  const float* b2 = (const float*)d_in[7];
  const float* Wo = (const float*)d_in[8];
  const float* bo = (const float*)d_in[9];
  int n = in_sizes[0];
  int e = in_sizes[1]/2;
  const int* src = ei;
  const int* dst = ei + e;
  float* y = (float*)d_out;

  int R2 = (n + NBUCK-1) / NBUCK;   // nodes per bucket (196 @ n=100k; must be <=256)

  char* p = (char*)d_ws;
  auto alloc = [&](size_t bytes)->void*{ void* r=p; p += (bytes+255)&~(size_t)255; return r; };
  int*    cnt  = (int*)   alloc((size_t)n*4);
  int*    off  = (int*)   alloc((size_t)n*4);
  int*    gcur = (int*)   alloc((size_t)NBUCK*4);
  float*  dis  = (float*) alloc((size_t)n*4);
  float*  xs   = (float*) alloc((size_t)n*4);
  uint*   tb   = (uint*)  alloc((size_t)(n+1)*4);           // +sentinel tb[n]=0
  float*  zb   = (float*) alloc((size_t)n*4);
  ushort* Wt1  = (ushort*)alloc((size_t)HDIM*HDIM*2);
  ushort* Wt2  = (ushort*)alloc((size_t)HDIM*HDIM*2);
  int*    cw   = (int*)   alloc((size_t)NBUCK*CWCAP*4);     // 16-padded segments
  uint*   bins = (uint*)  alloc((size_t)NBUCK*RECCAP*4);
  uint*   hb1  = (uint*)  alloc((size_t)n*64*4);
  uint*   gbuf = (uint*)  alloc((size_t)(n+64)*64*4);       // +64 rows pad for direct A-loads

  int nb = (n+255)/256;
  int mb = (n+63)/64;

  k_z512 <<<2,256,0,stream>>>(gcur);
  k_bin  <<<BINB,256,0,stream>>>(src,dst,gcur,bins,e,R2);
  k_csr  <<<NBUCK,256,0,stream>>>(bins,gcur,x,W1,W2,Wt1,Wt2,cnt,off,dis,xs,cw,n,R2);

  k_sagg    <<<(n+256)/256,256,0,stream>>>(xs,dis,off,cnt,cw,tb,n);
  k_wagg1s  <<<(n+3)/4,256,0,stream>>>(tb,off,cnt,cw,W0,b0,gbuf,n);
  k_mm      <<<mb,256,0,stream>>>(gbuf,Wt1,b1,dis,(ushort*)hb1,n);
  k_wagg    <<<(n+3)/4,256,0,stream>>>(hb1,off,cnt,cw,dis,gbuf,n);
  k_mmz     <<<mb,256,0,stream>>>(gbuf,Wt2,b2,Wo,dis,zb,n);
  k_final   <<<nb,256,0,stream>>>(zb,off,cnt,cw,dis,bo,y,n);
}

// Round 19
// 209.920 us; speedup vs baseline: 1.3544x; 1.0263x over previous
//
#include <hip/hip_runtime.h>
#include <math.h>

#define HDIM 128
#define NBUCK 512   // dst buckets; R2 = ceil(n/512) must be <= 256
#define BINB 256    // blocks in binning grid (>= nch so each block owns <=1 chunk)
#define CH 8192     // edges staged per chunk in k_bin
#define RECCAP 4096 // bin capacity per bucket (records; mean ~3136, +17 sigma)
#define CWCAP 8192  // cw capacity per bucket (16-padded segments; bound m+15*256 < 8192)

typedef unsigned int uint;
typedef unsigned short ushort;
typedef unsigned long long ull;
typedef __attribute__((ext_vector_type(8))) short short8;
typedef __attribute__((ext_vector_type(4))) float f32x4;

// bf16 helpers (bit-level; bf16->fp32 exact, fp32->bf16 RNE)
__device__ __forceinline__ float bflo(uint u){ return __uint_as_float(u<<16); }
__device__ __forceinline__ float bfhi(uint u){ return __uint_as_float(u&0xffff0000u); }
__device__ __forceinline__ ushort f2bf(float f){
  uint x = __float_as_uint(f);
  return (ushort)((x + 0x7fffu + ((x>>16)&1u)) >> 16);
}
__device__ __forceinline__ uint pack2bf(float a, float b){
  return (uint)f2bf(a) | ((uint)f2bf(b)<<16);
}

// ---------- zero the 512 bucket cursors ----------
__global__ void k_z512(int* gcur){
  int i = blockIdx.x*256 + threadIdx.x;
  if (i < NBUCK) gcur[i] = 0;
}

// ---------- single-pass chunked binning ----------
__global__ __launch_bounds__(256) void k_bin(const int* __restrict__ src, const int* __restrict__ dst,
                      int* __restrict__ gcur, uint* __restrict__ bins, int e, int R2){
  __shared__ uint   recs[CH];    // 32KB
  __shared__ ushort qarr[CH];    // 16KB
  __shared__ int    hist[NBUCK]; // 2KB
  __shared__ int    base[NBUCK]; // 2KB
  int t = threadIdx.x;
  int nch = (e + CH - 1)/CH;
  for (int c = blockIdx.x; c < nch; c += gridDim.x){
    int c0 = c*CH;
    int m = min(e - c0, CH);
    for (int u=t; u<NBUCK; u+=256) hist[u]=0;
    __syncthreads();
    for (int j=t; j<m; j+=256){
      int s = __builtin_nontemporal_load(&src[c0+j]);
      int d = __builtin_nontemporal_load(&dst[c0+j]);
      int q = d / R2;
      recs[j] = ((uint)s<<8) | (uint)(d - q*R2);
      qarr[j] = (ushort)q;
      atomicAdd(&hist[q],1);
    }
    __syncthreads();
    for (int u=t; u<NBUCK; u+=256){
      int cn = hist[u];
      base[u] = cn ? atomicAdd(&gcur[u], cn) : 0;
      hist[u] = 0;                       // reuse as placement cursor
    }
    __syncthreads();
    for (int j=t; j<m; j+=256){
      int q = qarr[j];
      int lp = base[q] + atomicAdd(&hist[q],1);
      if (lp < RECCAP) bins[q*RECCAP + lp] = recs[j];
    }
    __syncthreads();
  }
}

// ---------- per-bucket CSR build (block-local) + W transpose fold-in ----------
__global__ __launch_bounds__(256) void k_csr(const uint* __restrict__ bins, const int* __restrict__ gcur,
                      const float* __restrict__ x,
                      const float* __restrict__ W1, const float* __restrict__ W2,
                      ushort* __restrict__ Wt1, ushort* __restrict__ Wt2,
                      int* __restrict__ cnt, int* __restrict__ off,
                      float* __restrict__ dis, float* __restrict__ xs, int* __restrict__ cw,
                      int n, int R2){
  __shared__ uint recs[RECCAP];  // 16KB
  __shared__ int lcnt[256];
  __shared__ int lofs[256];
  __shared__ int tmp[256];
  int q = blockIdx.x;
  int t = threadIdx.x;
  if (q < 64){                   // Wt transpose: 64 blocks x 256 = 16384 entries
    int i = q*256 + t;
    int no = i>>7, k = i&127;
    Wt1[i] = f2bf(W1[k*HDIM+no]);
    Wt2[i] = f2bf(W2[k*HDIM+no]);
  }
  int d0 = q*R2;
  int nloc = min(n - d0, R2);
  if (nloc <= 0) return;
  int estart = q*CWCAP;          // padded cw segment base
  int m = min(gcur[q], RECCAP);
  lcnt[t] = 0;
  for (int i = t; i < m; i += 256) recs[i] = bins[(size_t)q*RECCAP + i];
  __syncthreads();
  for (int i = t; i < m; i += 256) atomicAdd(&lcnt[recs[i] & 255u], 1);
  __syncthreads();
  int v = (t<nloc) ? lcnt[t] : 0;
  int span = (v+15)&~15;         // 16-record aligned per-node segment
  tmp[t] = span; __syncthreads();
  for (int d=1; d<256; d<<=1){
    int a = (t>=d) ? tmp[t-d] : 0;
    __syncthreads(); tmp[t] += a; __syncthreads();
  }
  int excl = tmp[t] - span;
  if (t<nloc){
    int node = d0 + t;
    cnt[node] = v;
    off[node] = estart + excl;
    float dv = rsqrtf((float)(v+1));
    dis[node] = dv;
    xs[node] = dv*x[node];
    lofs[t] = excl;
    lcnt[t] = 0;                 // reuse as cursor
  }
  __syncthreads();
  for (int i = t; i < m; i += 256){
    uint r = recs[i];
    int dl = r & 255u;
    int pos = estart + lofs[dl] + atomicAdd(&lcnt[dl], 1);
    cw[pos] = (int)(r >> 8);
  }
  // fill pad slots with sentinel n (disjoint slots, no sync needed)
  if (t<nloc){
    int basep = estart + lofs[t];
    for (int j = v; j < span; ++j) cw[basep + j] = n;
  }
}

// ---------- scalar aggregation -> tb[i] = pack2bf(s_i, dis_i); tb[n]=0 sentinel ----------
__global__ void k_sagg(const float* __restrict__ xs, const float* __restrict__ dis,
                       const int* __restrict__ off, const int* __restrict__ cnt,
                       const int* __restrict__ cw, uint* __restrict__ tb, int n){
  int i = blockIdx.x*256 + threadIdx.x;
  if (i>n) return;
  if (i==n){ tb[n] = 0u; return; }     // sentinel: s=0, dis=0
  int b = off[i], e = b + cnt[i];
  float acc = xs[i];
  int k = b;
  for (; k+4<=e; k+=4){
    int4 s4 = *(const int4*)(cw + k);
    acc += (xs[s4.x]+xs[s4.y]) + (xs[s4.z]+xs[s4.w]);
  }
  for (; k<e; ++k) acc += xs[cw[k]];
  float dv = dis[i];
  tb[i] = pack2bf(dv*acc, dv);
}

// ---------- layer-1 aggregation, half-wave: 2 nodes/wave, 4 ch/lane ----------
// Lanes 0-31 own node i0, lanes 32-63 own node i0+1. One shfl serves BOTH
// halves (DS ops per edge halved). Pads/dead batches hit tb[n]=0 -> +0.0 exact.
__global__ __launch_bounds__(256) void k_wagg1s(const uint* __restrict__ tb, const int* __restrict__ off,
                       const int* __restrict__ cnt, const int* __restrict__ cw,
                       const float* __restrict__ W0, const float* __restrict__ b0,
                       uint* __restrict__ g, int n){
  int wave = threadIdx.x>>6, lane = threadIdx.x&63;
  int l32 = lane & 31;
  int i0 = blockIdx.x*8 + wave*2;
  if (i0 >= n) return;
  int i = i0 + (lane>>5);
  bool alive = i < n;
  float4 w0 = ((const float4*)W0)[l32];
  float4 b0v = ((const float4*)b0)[l32];
  int cA = cnt[i0];
  int cB = (i0+1 < n) ? cnt[i0+1] : 0;
  int myC = alive ? ((lane>=32) ? cB : cA) : 0;
  int myNB = (myC+15)>>4;
  int nbMax = (max(cA,cB)+15)>>4;
  int myOff = alive ? off[i] : 0;
  uint ui = alive ? tb[i] : 0u;
  float si = bflo(ui), di = bfhi(ui);
  f32x4 acc;
  acc[0] = di * fmaxf(fmaf(si, w0.x, b0v.x), 0.f);
  acc[1] = di * fmaxf(fmaf(si, w0.y, b0v.y), 0.f);
  acc[2] = di * fmaxf(fmaf(si, w0.z, b0v.z), 0.f);
  acc[3] = di * fmaxf(fmaf(si, w0.w, b0v.w), 0.f);
  int l16 = lane & 15;
  int bsel = lane & 32;
  for (int bt = 0; bt < nbMax; ++bt){
    // loader lanes (l32<16): own half's 16 edge indices; dead batches -> sentinel
    int idx = (l32 < 16 && bt < myNB) ? cw[myOff + bt*16 + l16] : n;
    uint tt = tb[idx];
    #pragma unroll
    for (int j=0;j<16;j++){
      uint u = (uint)__shfl((int)tt, bsel + j);   // per-half broadcast, one DS op
      float sj = bflo(u), dj = bfhi(u);
      acc[0] = fmaf(dj, fmaxf(fmaf(sj, w0.x, b0v.x), 0.f), acc[0]);
      acc[1] = fmaf(dj, fmaxf(fmaf(sj, w0.y, b0v.y), 0.f), acc[1]);
      acc[2] = fmaf(dj, fmaxf(fmaf(sj, w0.z, b0v.z), 0.f), acc[2]);
      acc[3] = fmaf(dj, fmaxf(fmaf(sj, w0.w, b0v.w), 0.f), acc[3]);
    }
  }
  if (alive){
    ull o = (ull)pack2bf(di*acc[0], di*acc[1]) |
            ((ull)pack2bf(di*acc[2], di*acc[3]) << 32);
    __builtin_nontemporal_store(o, (ull*)(g + (size_t)i*64) + l32);
  }
}

// ---------- wide aggregation: g_i = dis_i*(hs_i + sum hs[src]); exact cnt ----------
__global__ __launch_bounds__(256) void k_wagg(const uint* __restrict__ h, const int* __restrict__ off,
                       const int* __restrict__ cnt, const int* __restrict__ cw,
                       const float* __restrict__ dis, uint* __restrict__ g, int n){
  int wave = threadIdx.x>>6, lane = threadIdx.x&63;
  int i = blockIdx.x*4 + wave;
  if (i>=n) return;
  int b = off[i], e = b + cnt[i];
  uint su = h[(size_t)i*64 + lane];
  float2 acc; acc.x = bflo(su); acc.y = bfhi(su);
  int k = b;
  for (; k+16<=e; k+=16){
    const int4* c4 = (const int4*)(cw + k);   // b is 16-element aligned
    int4 v0 = c4[0], v1 = c4[1], v2 = c4[2], v3 = c4[3];
    int v[16] = {v0.x,v0.y,v0.z,v0.w, v1.x,v1.y,v1.z,v1.w,
                 v2.x,v2.y,v2.z,v2.w, v3.x,v3.y,v3.z,v3.w};
    uint u[16];
    #pragma unroll
    for (int j=0;j<16;j++) u[j] = h[(size_t)v[j]*64 + lane];
    #pragma unroll
    for (int j=0;j<16;j++){ acc.x += bflo(u[j]); acc.y += bfhi(u[j]); }
  }
  for (; k+4<=e; k+=4){
    int4 v4 = *(const int4*)(cw + k);
    uint u0 = h[(size_t)v4.x*64 + lane];
    uint u1 = h[(size_t)v4.y*64 + lane];
    uint u2 = h[(size_t)v4.z*64 + lane];
    uint u3 = h[(size_t)v4.w*64 + lane];
    acc.x += bflo(u0)+bflo(u1)+bflo(u2)+bflo(u3);
    acc.y += bfhi(u0)+bfhi(u1)+bfhi(u2)+bfhi(u3);
  }
  for (; k<e; ++k){
    uint u = h[(size_t)cw[k]*64 + lane];
    acc.x += bflo(u); acc.y += bfhi(u);
  }
  float dv = dis[i];
  __builtin_nontemporal_store(pack2bf(dv*acc.x, dv*acc.y), &g[(size_t)i*64 + lane]);
}

// ---------- dense via MFMA: hs1 = dis*relu(g @ W1 + b1); A direct from global ----------
__global__ __launch_bounds__(256) void k_mm(const uint* __restrict__ g, const ushort* __restrict__ Wt,
                     const float* __restrict__ b, const float* __restrict__ dis,
                     ushort* __restrict__ h, int n){
  __shared__ uint4 Ws4[2048];   // Wt[128][128] bf16, swizzled, 32KB
  int t = threadIdx.x;
  int n0 = blockIdx.x*64;

  const uint4* Wg = (const uint4*)Wt;
  #pragma unroll
  for (int i=0;i<8;i++){
    int c = t + i*256;
    int row = c>>4, slot = c&15;
    Ws4[row*16 + (slot^(row&7))] = Wg[c];
  }

  int w = t>>6, l = t&63;
  int lr = l&15, lg = l>>4;
  const uint4* Gg = (const uint4*)g;
  size_t arow = (size_t)(n0 + 16*w + lr)*16;
  uint4 a4[4];
  #pragma unroll
  for (int s=0;s<4;s++) a4[s] = Gg[arow + 4*s + lg];   // padded gbuf: safe past n

  __syncthreads();

  f32x4 acc[8];
  #pragma unroll
  for (int j=0;j<8;j++) acc[j] = (f32x4){0.f,0.f,0.f,0.f};

  float bv[8];
  #pragma unroll
  for (int j=0;j<8;j++) bv[j] = b[16*j + lr];

  #pragma unroll
  for (int s=0;s<4;s++){
    short8 a = *(const short8*)&a4[s];
    #pragma unroll
    for (int j=0;j<8;j++){
      short8 bb = *(const short8*)&Ws4[(16*j + lr)*16 + ((4*s + lg)^(lr&7))];
      acc[j] = __builtin_amdgcn_mfma_f32_16x16x32_bf16(a, bb, acc[j], 0, 0, 0);
    }
  }

  #pragma unroll
  for (int j=0;j<8;j++){
    int col = 16*j + lr;
    #pragma unroll
    for (int q=0;q<4;q++){
      int node = n0 + 16*w + lg*4 + q;
      if (node < n){
        float v = dis[node]*fmaxf(acc[j][q] + bv[j], 0.f);
        h[(size_t)node*HDIM + col] = f2bf(v);
      }
    }
  }
}

// ---------- mm2 fused with z: zs = dis*dot(relu(g@W2+b2), Wo); A direct ----------
__global__ __launch_bounds__(256) void k_mmz(const uint* __restrict__ g, const ushort* __restrict__ Wt,
                     const float* __restrict__ b, const float* __restrict__ Wo,
                     const float* __restrict__ dis, float* __restrict__ zs, int n){
  __shared__ uint4 Ws4[2048];
  int t = threadIdx.x;
  int n0 = blockIdx.x*64;

  const uint4* Wg = (const uint4*)Wt;
  #pragma unroll
  for (int i=0;i<8;i++){
    int c = t + i*256;
    int row = c>>4, slot = c&15;
    Ws4[row*16 + (slot^(row&7))] = Wg[c];
  }

  int w = t>>6, l = t&63;
  int lr = l&15, lg = l>>4;
  const uint4* Gg = (const uint4*)g;
  size_t arow = (size_t)(n0 + 16*w + lr)*16;
  uint4 a4[4];
  #pragma unroll
  for (int s=0;s<4;s++) a4[s] = Gg[arow + 4*s + lg];

  __syncthreads();

  f32x4 acc[8];
  #pragma unroll
  for (int j=0;j<8;j++) acc[j] = (f32x4){0.f,0.f,0.f,0.f};

  float bv[8], wo[8];
  #pragma unroll
  for (int j=0;j<8;j++){ bv[j] = b[16*j + lr]; wo[j] = Wo[16*j + lr]; }

  #pragma unroll
  for (int s=0;s<4;s++){
    short8 a = *(const short8*)&a4[s];
    #pragma unroll
    for (int j=0;j<8;j++){
      short8 bb = *(const short8*)&Ws4[(16*j + lr)*16 + ((4*s + lg)^(lr&7))];
      acc[j] = __builtin_amdgcn_mfma_f32_16x16x32_bf16(a, bb, acc[j], 0, 0, 0);
    }
  }

  float zacc[4] = {0.f,0.f,0.f,0.f};
  #pragma unroll
  for (int j=0;j<8;j++){
    #pragma unroll
    for (int q=0;q<4;q++){
      float r = fmaxf(acc[j][q] + bv[j], 0.f);
      zacc[q] = fmaf(r, wo[j], zacc[q]);
    }
  }
  #pragma unroll
  for (int m=1;m<16;m<<=1){
    #pragma unroll
    for (int q=0;q<4;q++) zacc[q] += __shfl_xor(zacc[q], m);
  }
  if (lr==0){
    #pragma unroll
    for (int q=0;q<4;q++){
      int node = n0 + 16*w + lg*4 + q;
      if (node < n) zs[node] = dis[node]*zacc[q];
    }
  }
}

// ---------- y_i = sigmoid(dis_i*(zs_i + sum zs[src]) + bo) ----------
__global__ void k_final(const float* __restrict__ zs, const int* __restrict__ off, const int* __restrict__ cnt,
                        const int* __restrict__ cw, const float* __restrict__ dis,
                        const float* __restrict__ bo, float* __restrict__ y, int n){
  int i = blockIdx.x*256 + threadIdx.x;
  if (i>=n) return;
  int b = off[i], e = b + cnt[i];
  float acc = zs[i];
  int k = b;
  for (; k+4<=e; k+=4){
    int4 s4 = *(const int4*)(cw + k);
    acc += (zs[s4.x]+zs[s4.y]) + (zs[s4.z]+zs[s4.w]);
  }
  for (; k<e; ++k) acc += zs[cw[k]];
  float v = dis[i]*acc + bo[0];
  y[i] = 1.f/(1.f + expf(-v));
}

extern "C" void kernel_launch(void* const* d_in, const int* in_sizes, int n_in,
                              void* d_out, int out_size, void* d_ws, size_t ws_size,
                              hipStream_t stream){
  const float* x  = (const float*)d_in[0];
  const int*   ei = (const int*)d_in[1];
  const float* W0 = (const float*)d_in[2];
  const float* b0 = (const float*)d_in[3];
  const float* W1 = (const float*)d_in[4];
  const float* b1 = (const float*)d_in[5];
  const float* W2 = (const float*)d_in[6];
  const float* b2 = (const float*)d_in[7];
  const float* Wo = (const float*)d_in[8];
  const float* bo = (const float*)d_in[9];
  int n = in_sizes[0];
  int e = in_sizes[1]/2;
  const int* src = ei;
  const int* dst = ei + e;
  float* y = (float*)d_out;

  int R2 = (n + NBUCK-1) / NBUCK;   // nodes per bucket (196 @ n=100k; must be <=256)

  char* p = (char*)d_ws;
  auto alloc = [&](size_t bytes)->void*{ void* r=p; p += (bytes+255)&~(size_t)255; return r; };
  int*    cnt  = (int*)   alloc((size_t)n*4);
  int*    off  = (int*)   alloc((size_t)n*4);
  int*    gcur = (int*)   alloc((size_t)NBUCK*4);
  float*  dis  = (float*) alloc((size_t)n*4);
  float*  xs   = (float*) alloc((size_t)n*4);
  uint*   tb   = (uint*)  alloc((size_t)(n+1)*4);           // +sentinel tb[n]=0
  float*  zb   = (float*) alloc((size_t)n*4);
  ushort* Wt1  = (ushort*)alloc((size_t)HDIM*HDIM*2);
  ushort* Wt2  = (ushort*)alloc((size_t)HDIM*HDIM*2);
  int*    cw   = (int*)   alloc((size_t)NBUCK*CWCAP*4);     // 16-padded segments
  uint*   bins = (uint*)  alloc((size_t)NBUCK*RECCAP*4);
  uint*   hb1  = (uint*)  alloc((size_t)n*64*4);
  uint*   gbuf = (uint*)  alloc((size_t)(n+64)*64*4);       // +64 rows pad for direct A-loads

  int nb = (n+255)/256;
  int mb = (n+63)/64;

  k_z512 <<<2,256,0,stream>>>(gcur);
  k_bin  <<<BINB,256,0,stream>>>(src,dst,gcur,bins,e,R2);
  k_csr  <<<NBUCK,256,0,stream>>>(bins,gcur,x,W1,W2,Wt1,Wt2,cnt,off,dis,xs,cw,n,R2);

  k_sagg    <<<(n+256)/256,256,0,stream>>>(xs,dis,off,cnt,cw,tb,n);
  k_wagg1s  <<<(n+7)/8,256,0,stream>>>(tb,off,cnt,cw,W0,b0,gbuf,n);
  k_mm      <<<mb,256,0,stream>>>(gbuf,Wt1,b1,dis,(ushort*)hb1,n);
  k_wagg    <<<(n+3)/4,256,0,stream>>>(hb1,off,cnt,cw,dis,gbuf,n);
  k_mmz     <<<mb,256,0,stream>>>(gbuf,Wt2,b2,Wo,dis,zb,n);
  k_final   <<<nb,256,0,stream>>>(zb,off,cnt,cw,dis,bo,y,n);
}

// Round 20
// 209.042 us; speedup vs baseline: 1.3601x; 1.0042x over previous
//
#include <hip/hip_runtime.h>
#include <math.h>

#define HDIM 128
#define NBUCK 512   // dst buckets; R2 = ceil(n/512) must be <= 256
#define BINB 256    // blocks in binning grid (>= nch so each block owns <=1 chunk)
#define CH 8192     // edges staged per chunk in k_bin
#define RECCAP 4096 // bin capacity per bucket (records; mean ~3136, +17 sigma)
#define CWCAP 8192  // cw capacity per bucket (16-padded segments; bound m+15*256 < 8192)

typedef unsigned int uint;
typedef unsigned short ushort;
typedef unsigned long long ull;
typedef __attribute__((ext_vector_type(8))) short short8;
typedef __attribute__((ext_vector_type(4))) float f32x4;

// bf16 helpers (bit-level; bf16->fp32 exact, fp32->bf16 RNE)
__device__ __forceinline__ float bflo(uint u){ return __uint_as_float(u<<16); }
__device__ __forceinline__ float bfhi(uint u){ return __uint_as_float(u&0xffff0000u); }
__device__ __forceinline__ ushort f2bf(float f){
  uint x = __float_as_uint(f);
  return (ushort)((x + 0x7fffu + ((x>>16)&1u)) >> 16);
}
__device__ __forceinline__ uint pack2bf(float a, float b){
  return (uint)f2bf(a) | ((uint)f2bf(b)<<16);
}

// ---------- zero the 512 bucket cursors ----------
__global__ void k_z512(int* gcur){
  int i = blockIdx.x*256 + threadIdx.x;
  if (i < NBUCK) gcur[i] = 0;
}

// ---------- single-pass chunked binning ----------
__global__ __launch_bounds__(256) void k_bin(const int* __restrict__ src, const int* __restrict__ dst,
                      int* __restrict__ gcur, uint* __restrict__ bins, int e, int R2){
  __shared__ uint   recs[CH];    // 32KB
  __shared__ ushort qarr[CH];    // 16KB
  __shared__ int    hist[NBUCK]; // 2KB
  __shared__ int    base[NBUCK]; // 2KB
  int t = threadIdx.x;
  int nch = (e + CH - 1)/CH;
  for (int c = blockIdx.x; c < nch; c += gridDim.x){
    int c0 = c*CH;
    int m = min(e - c0, CH);
    for (int u=t; u<NBUCK; u+=256) hist[u]=0;
    __syncthreads();
    for (int j=t; j<m; j+=256){
      int s = __builtin_nontemporal_load(&src[c0+j]);
      int d = __builtin_nontemporal_load(&dst[c0+j]);
      int q = d / R2;
      recs[j] = ((uint)s<<8) | (uint)(d - q*R2);
      qarr[j] = (ushort)q;
      atomicAdd(&hist[q],1);
    }
    __syncthreads();
    for (int u=t; u<NBUCK; u+=256){
      int cn = hist[u];
      base[u] = cn ? atomicAdd(&gcur[u], cn) : 0;
      hist[u] = 0;                       // reuse as placement cursor
    }
    __syncthreads();
    for (int j=t; j<m; j+=256){
      int q = qarr[j];
      int lp = base[q] + atomicAdd(&hist[q],1);
      if (lp < RECCAP) bins[q*RECCAP + lp] = recs[j];
    }
    __syncthreads();
  }
}

// ---------- per-bucket CSR build (block-local) + W transpose fold-in ----------
__global__ __launch_bounds__(256) void k_csr(const uint* __restrict__ bins, const int* __restrict__ gcur,
                      const float* __restrict__ x,
                      const float* __restrict__ W1, const float* __restrict__ W2,
                      ushort* __restrict__ Wt1, ushort* __restrict__ Wt2,
                      int* __restrict__ cnt, int* __restrict__ off,
                      float* __restrict__ dis, float* __restrict__ xs, int* __restrict__ cw,
                      int n, int R2){
  __shared__ uint recs[RECCAP];  // 16KB
  __shared__ int lcnt[256];
  __shared__ int lofs[256];
  __shared__ int tmp[256];
  int q = blockIdx.x;
  int t = threadIdx.x;
  if (q < 64){                   // Wt transpose: 64 blocks x 256 = 16384 entries
    int i = q*256 + t;
    int no = i>>7, k = i&127;
    Wt1[i] = f2bf(W1[k*HDIM+no]);
    Wt2[i] = f2bf(W2[k*HDIM+no]);
  }
  int d0 = q*R2;
  int nloc = min(n - d0, R2);
  if (nloc <= 0) return;
  int estart = q*CWCAP;          // padded cw segment base
  int m = min(gcur[q], RECCAP);
  lcnt[t] = 0;
  for (int i = t; i < m; i += 256) recs[i] = bins[(size_t)q*RECCAP + i];
  __syncthreads();
  for (int i = t; i < m; i += 256) atomicAdd(&lcnt[recs[i] & 255u], 1);
  __syncthreads();
  int v = (t<nloc) ? lcnt[t] : 0;
  int span = (v+15)&~15;         // 16-record aligned per-node segment
  tmp[t] = span; __syncthreads();
  for (int d=1; d<256; d<<=1){
    int a = (t>=d) ? tmp[t-d] : 0;
    __syncthreads(); tmp[t] += a; __syncthreads();
  }
  int excl = tmp[t] - span;
  if (t<nloc){
    int node = d0 + t;
    cnt[node] = v;
    off[node] = estart + excl;
    float dv = rsqrtf((float)(v+1));
    dis[node] = dv;
    xs[node] = dv*x[node];
    lofs[t] = excl;
    lcnt[t] = 0;                 // reuse as cursor
  }
  __syncthreads();
  for (int i = t; i < m; i += 256){
    uint r = recs[i];
    int dl = r & 255u;
    int pos = estart + lofs[dl] + atomicAdd(&lcnt[dl], 1);
    cw[pos] = (int)(r >> 8);
  }
  // fill pad slots with sentinel n (disjoint slots, no sync needed)
  if (t<nloc){
    int basep = estart + lofs[t];
    for (int j = v; j < span; ++j) cw[basep + j] = n;
  }
}

// ---------- scalar aggregation -> tb[i] = pack2bf(s_i, dis_i); tb[n]=0 sentinel ----------
__global__ void k_sagg(const float* __restrict__ xs, const float* __restrict__ dis,
                       const int* __restrict__ off, const int* __restrict__ cnt,
                       const int* __restrict__ cw, uint* __restrict__ tb, int n){
  int i = blockIdx.x*256 + threadIdx.x;
  if (i>n) return;
  if (i==n){ tb[n] = 0u; return; }     // sentinel: s=0, dis=0
  int b = off[i], e = b + cnt[i];
  float acc = xs[i];
  int k = b;
  for (; k+4<=e; k+=4){
    int4 s4 = *(const int4*)(cw + k);
    acc += (xs[s4.x]+xs[s4.y]) + (xs[s4.z]+xs[s4.w]);
  }
  for (; k<e; ++k) acc += xs[cw[k]];
  float dv = dis[i];
  tb[i] = pack2bf(dv*acc, dv);
}

// ---------- layer-1 aggregation, quarter-wave: 4 nodes/wave, 8 ch/lane ----------
// 16 lanes own each node; one shfl (ds_bpermute, per-lane index lane&48 + j)
// broadcasts each edge to all FOUR quarters at once. Pads hit tb[n]=0 -> +0.0.
__global__ __launch_bounds__(256) void k_wagg1s(const uint* __restrict__ tb, const int* __restrict__ off,
                       const int* __restrict__ cnt, const int* __restrict__ cw,
                       const float* __restrict__ W0, const float* __restrict__ b0,
                       uint* __restrict__ g, int n){
  int wave = threadIdx.x>>6, lane = threadIdx.x&63;
  int l16 = lane & 15;
  int i0 = blockIdx.x*16 + wave*4;
  if (i0 >= n) return;
  int qd = lane>>4;                 // quarter 0..3
  int i = i0 + qd;
  bool alive = i < n;
  // 8 channels per lane: ch = l16*8 .. l16*8+7
  float4 w0a = ((const float4*)W0)[l16*2];
  float4 w0b = ((const float4*)W0)[l16*2+1];
  float4 b0a = ((const float4*)b0)[l16*2];
  float4 b0b = ((const float4*)b0)[l16*2+1];
  int c0 = cnt[i0];
  int c1 = (i0+1<n) ? cnt[i0+1] : 0;
  int c2 = (i0+2<n) ? cnt[i0+2] : 0;
  int c3 = (i0+3<n) ? cnt[i0+3] : 0;
  int myC = (qd==0) ? c0 : (qd==1) ? c1 : (qd==2) ? c2 : c3;
  int myNB = (myC+15)>>4;
  int nbMax = (max(max(c0,c1),max(c2,c3))+15)>>4;
  int myOff = alive ? off[i] : 0;
  uint ui = alive ? tb[i] : 0u;
  float si = bflo(ui), di = bfhi(ui);
  f32x4 accA, accB;
  accA[0] = di * fmaxf(fmaf(si, w0a.x, b0a.x), 0.f);
  accA[1] = di * fmaxf(fmaf(si, w0a.y, b0a.y), 0.f);
  accA[2] = di * fmaxf(fmaf(si, w0a.z, b0a.z), 0.f);
  accA[3] = di * fmaxf(fmaf(si, w0a.w, b0a.w), 0.f);
  accB[0] = di * fmaxf(fmaf(si, w0b.x, b0b.x), 0.f);
  accB[1] = di * fmaxf(fmaf(si, w0b.y, b0b.y), 0.f);
  accB[2] = di * fmaxf(fmaf(si, w0b.z, b0b.z), 0.f);
  accB[3] = di * fmaxf(fmaf(si, w0b.w, b0b.w), 0.f);
  int bsel = lane & 48;
  for (int bt = 0; bt < nbMax; ++bt){
    // every lane loads edge-slot l16 of its own node; dead batches -> sentinel
    int idx = (bt < myNB) ? cw[myOff + bt*16 + l16] : n;
    uint tt = tb[idx];
    #pragma unroll
    for (int j=0;j<16;j++){
      uint u = (uint)__shfl((int)tt, bsel + j);   // per-quarter broadcast, one DS op
      float sj = bflo(u), dj = bfhi(u);
      accA[0] = fmaf(dj, fmaxf(fmaf(sj, w0a.x, b0a.x), 0.f), accA[0]);
      accA[1] = fmaf(dj, fmaxf(fmaf(sj, w0a.y, b0a.y), 0.f), accA[1]);
      accA[2] = fmaf(dj, fmaxf(fmaf(sj, w0a.z, b0a.z), 0.f), accA[2]);
      accA[3] = fmaf(dj, fmaxf(fmaf(sj, w0a.w, b0a.w), 0.f), accA[3]);
      accB[0] = fmaf(dj, fmaxf(fmaf(sj, w0b.x, b0b.x), 0.f), accB[0]);
      accB[1] = fmaf(dj, fmaxf(fmaf(sj, w0b.y, b0b.y), 0.f), accB[1]);
      accB[2] = fmaf(dj, fmaxf(fmaf(sj, w0b.z, b0b.z), 0.f), accB[2]);
      accB[3] = fmaf(dj, fmaxf(fmaf(sj, w0b.w, b0b.w), 0.f), accB[3]);
    }
  }
  if (alive){
    ull o1 = (ull)pack2bf(di*accA[0], di*accA[1]) |
             ((ull)pack2bf(di*accA[2], di*accA[3]) << 32);
    ull o2 = (ull)pack2bf(di*accB[0], di*accB[1]) |
             ((ull)pack2bf(di*accB[2], di*accB[3]) << 32);
    ull* dst8 = (ull*)(g + (size_t)i*64) + l16*2;
    __builtin_nontemporal_store(o1, dst8);
    __builtin_nontemporal_store(o2, dst8 + 1);
  }
}

// ---------- wide aggregation: g_i = dis_i*(hs_i + sum hs[src]); exact cnt ----------
__global__ __launch_bounds__(256) void k_wagg(const uint* __restrict__ h, const int* __restrict__ off,
                       const int* __restrict__ cnt, const int* __restrict__ cw,
                       const float* __restrict__ dis, uint* __restrict__ g, int n){
  int wave = threadIdx.x>>6, lane = threadIdx.x&63;
  int i = blockIdx.x*4 + wave;
  if (i>=n) return;
  int b = off[i], e = b + cnt[i];
  uint su = h[(size_t)i*64 + lane];
  float2 acc; acc.x = bflo(su); acc.y = bfhi(su);
  int k = b;
  for (; k+16<=e; k+=16){
    const int4* c4 = (const int4*)(cw + k);   // b is 16-element aligned
    int4 v0 = c4[0], v1 = c4[1], v2 = c4[2], v3 = c4[3];
    int v[16] = {v0.x,v0.y,v0.z,v0.w, v1.x,v1.y,v1.z,v1.w,
                 v2.x,v2.y,v2.z,v2.w, v3.x,v3.y,v3.z,v3.w};
    uint u[16];
    #pragma unroll
    for (int j=0;j<16;j++) u[j] = h[(size_t)v[j]*64 + lane];
    #pragma unroll
    for (int j=0;j<16;j++){ acc.x += bflo(u[j]); acc.y += bfhi(u[j]); }
  }
  for (; k+4<=e; k+=4){
    int4 v4 = *(const int4*)(cw + k);
    uint u0 = h[(size_t)v4.x*64 + lane];
    uint u1 = h[(size_t)v4.y*64 + lane];
    uint u2 = h[(size_t)v4.z*64 + lane];
    uint u3 = h[(size_t)v4.w*64 + lane];
    acc.x += bflo(u0)+bflo(u1)+bflo(u2)+bflo(u3);
    acc.y += bfhi(u0)+bfhi(u1)+bfhi(u2)+bfhi(u3);
  }
  for (; k<e; ++k){
    uint u = h[(size_t)cw[k]*64 + lane];
    acc.x += bflo(u); acc.y += bfhi(u);
  }
  float dv = dis[i];
  __builtin_nontemporal_store(pack2bf(dv*acc.x, dv*acc.y), &g[(size_t)i*64 + lane]);
}

// ---------- dense via MFMA: hs1 = dis*relu(g @ W1 + b1); A direct from global ----------
__global__ __launch_bounds__(256) void k_mm(const uint* __restrict__ g, const ushort* __restrict__ Wt,
                     const float* __restrict__ b, const float* __restrict__ dis,
                     ushort* __restrict__ h, int n){
  __shared__ uint4 Ws4[2048];   // Wt[128][128] bf16, swizzled, 32KB
  int t = threadIdx.x;
  int n0 = blockIdx.x*64;

  const uint4* Wg = (const uint4*)Wt;
  #pragma unroll
  for (int i=0;i<8;i++){
    int c = t + i*256;
    int row = c>>4, slot = c&15;
    Ws4[row*16 + (slot^(row&7))] = Wg[c];
  }

  int w = t>>6, l = t&63;
  int lr = l&15, lg = l>>4;
  const uint4* Gg = (const uint4*)g;
  size_t arow = (size_t)(n0 + 16*w + lr)*16;
  uint4 a4[4];
  #pragma unroll
  for (int s=0;s<4;s++) a4[s] = Gg[arow + 4*s + lg];   // padded gbuf: safe past n

  __syncthreads();

  f32x4 acc[8];
  #pragma unroll
  for (int j=0;j<8;j++) acc[j] = (f32x4){0.f,0.f,0.f,0.f};

  float bv[8];
  #pragma unroll
  for (int j=0;j<8;j++) bv[j] = b[16*j + lr];

  #pragma unroll
  for (int s=0;s<4;s++){
    short8 a = *(const short8*)&a4[s];
    #pragma unroll
    for (int j=0;j<8;j++){
      short8 bb = *(const short8*)&Ws4[(16*j + lr)*16 + ((4*s + lg)^(lr&7))];
      acc[j] = __builtin_amdgcn_mfma_f32_16x16x32_bf16(a, bb, acc[j], 0, 0, 0);
    }
  }

  #pragma unroll
  for (int j=0;j<8;j++){
    int col = 16*j + lr;
    #pragma unroll
    for (int q=0;q<4;q++){
      int node = n0 + 16*w + lg*4 + q;
      if (node < n){
        float v = dis[node]*fmaxf(acc[j][q] + bv[j], 0.f);
        h[(size_t)node*HDIM + col] = f2bf(v);
      }
    }
  }
}

// ---------- mm2 fused with z: zs = dis*dot(relu(g@W2+b2), Wo); A direct ----------
__global__ __launch_bounds__(256) void k_mmz(const uint* __restrict__ g, const ushort* __restrict__ Wt,
                     const float* __restrict__ b, const float* __restrict__ Wo,
                     const float* __restrict__ dis, float* __restrict__ zs, int n){
  __shared__ uint4 Ws4[2048];
  int t = threadIdx.x;
  int n0 = blockIdx.x*64;

  const uint4* Wg = (const uint4*)Wt;
  #pragma unroll
  for (int i=0;i<8;i++){
    int c = t + i*256;
    int row = c>>4, slot = c&15;
    Ws4[row*16 + (slot^(row&7))] = Wg[c];
  }

  int w = t>>6, l = t&63;
  int lr = l&15, lg = l>>4;
  const uint4* Gg = (const uint4*)g;
  size_t arow = (size_t)(n0 + 16*w + lr)*16;
  uint4 a4[4];
  #pragma unroll
  for (int s=0;s<4;s++) a4[s] = Gg[arow + 4*s + lg];

  __syncthreads();

  f32x4 acc[8];
  #pragma unroll
  for (int j=0;j<8;j++) acc[j] = (f32x4){0.f,0.f,0.f,0.f};

  float bv[8], wo[8];
  #pragma unroll
  for (int j=0;j<8;j++){ bv[j] = b[16*j + lr]; wo[j] = Wo[16*j + lr]; }

  #pragma unroll
  for (int s=0;s<4;s++){
    short8 a = *(const short8*)&a4[s];
    #pragma unroll
    for (int j=0;j<8;j++){
      short8 bb = *(const short8*)&Ws4[(16*j + lr)*16 + ((4*s + lg)^(lr&7))];
      acc[j] = __builtin_amdgcn_mfma_f32_16x16x32_bf16(a, bb, acc[j], 0, 0, 0);
    }
  }

  float zacc[4] = {0.f,0.f,0.f,0.f};
  #pragma unroll
  for (int j=0;j<8;j++){
    #pragma unroll
    for (int q=0;q<4;q++){
      float r = fmaxf(acc[j][q] + bv[j], 0.f);
      zacc[q] = fmaf(r, wo[j], zacc[q]);
    }
  }
  #pragma unroll
  for (int m=1;m<16;m<<=1){
    #pragma unroll
    for (int q=0;q<4;q++) zacc[q] += __shfl_xor(zacc[q], m);
  }
  if (lr==0){
    #pragma unroll
    for (int q=0;q<4;q++){
      int node = n0 + 16*w + lg*4 + q;
      if (node < n) zs[node] = dis[node]*zacc[q];
    }
  }
}

// ---------- y_i = sigmoid(dis_i*(zs_i + sum zs[src]) + bo) ----------
__global__ void k_final(const float* __restrict__ zs, const int* __restrict__ off, const int* __restrict__ cnt,
                        const int* __restrict__ cw, const float* __restrict__ dis,
                        const float* __restrict__ bo, float* __restrict__ y, int n){
  int i = blockIdx.x*256 + threadIdx.x;
  if (i>=n) return;
  int b = off[i], e = b + cnt[i];
  float acc = zs[i];
  int k = b;
  for (; k+4<=e; k+=4){
    int4 s4 = *(const int4*)(cw + k);
    acc += (zs[s4.x]+zs[s4.y]) + (zs[s4.z]+zs[s4.w]);
  }
  for (; k<e; ++k) acc += zs[cw[k]];
  float v = dis[i]*acc + bo[0];
  y[i] = 1.f/(1.f + expf(-v));
}

extern "C" void kernel_launch(void* const* d_in, const int* in_sizes, int n_in,
                              void* d_out, int out_size, void* d_ws, size_t ws_size,
                              hipStream_t stream){
  const float* x  = (const float*)d_in[0];
  const int*   ei = (const int*)d_in[1];
  const float* W0 = (const float*)d_in[2];
  const float* b0 = (const float*)d_in[3];
  const float* W1 = (const float*)d_in[4];
  const float* b1 = (const float*)d_in[5];
  const float* W2 = (const float*)d_in[6];
  const float* b2 = (const float*)d_in[7];
  const float* Wo = (const float*)d_in[8];
  const float* bo = (const float*)d_in[9];
  int n = in_sizes[0];
  int e = in_sizes[1]/2;
  const int* src = ei;
  const int* dst = ei + e;
  float* y = (float*)d_out;

  int R2 = (n + NBUCK-1) / NBUCK;   // nodes per bucket (196 @ n=100k; must be <=256)

  char* p = (char*)d_ws;
  auto alloc = [&](size_t bytes)->void*{ void* r=p; p += (bytes+255)&~(size_t)255; return r; };
  int*    cnt  = (int*)   alloc((size_t)n*4);
  int*    off  = (int*)   alloc((size_t)n*4);
  int*    gcur = (int*)   alloc((size_t)NBUCK*4);
  float*  dis  = (float*) alloc((size_t)n*4);
  float*  xs   = (float*) alloc((size_t)n*4);
  uint*   tb   = (uint*)  alloc((size_t)(n+1)*4);           // +sentinel tb[n]=0
  float*  zb   = (float*) alloc((size_t)n*4);
  ushort* Wt1  = (ushort*)alloc((size_t)HDIM*HDIM*2);
  ushort* Wt2  = (ushort*)alloc((size_t)HDIM*HDIM*2);
  int*    cw   = (int*)   alloc((size_t)NBUCK*CWCAP*4);     // 16-padded segments
  uint*   bins = (uint*)  alloc((size_t)NBUCK*RECCAP*4);
  uint*   hb1  = (uint*)  alloc((size_t)n*64*4);
  uint*   gbuf = (uint*)  alloc((size_t)(n+64)*64*4);       // +64 rows pad for direct A-loads

  int nb = (n+255)/256;
  int mb = (n+63)/64;

  k_z512 <<<2,256,0,stream>>>(gcur);
  k_bin  <<<BINB,256,0,stream>>>(src,dst,gcur,bins,e,R2);
  k_csr  <<<NBUCK,256,0,stream>>>(bins,gcur,x,W1,W2,Wt1,Wt2,cnt,off,dis,xs,cw,n,R2);

  k_sagg    <<<(n+256)/256,256,0,stream>>>(xs,dis,off,cnt,cw,tb,n);
  k_wagg1s  <<<(n+15)/16,256,0,stream>>>(tb,off,cnt,cw,W0,b0,gbuf,n);
  k_mm      <<<mb,256,0,stream>>>(gbuf,Wt1,b1,dis,(ushort*)hb1,n);
  k_wagg    <<<(n+3)/4,256,0,stream>>>(hb1,off,cnt,cw,dis,gbuf,n);
  k_mmz     <<<mb,256,0,stream>>>(gbuf,Wt2,b2,Wo,dis,zb,n);
  k_final   <<<nb,256,0,stream>>>(zb,off,cnt,cw,dis,bo,y,n);
}